// Round 3
// baseline (401.502 us; speedup 1.0000x reference)
//
#include <hip/hip_runtime.h>
#include <math.h>

#define NBATCH 32
#define S      49152
#define NF     24          // frames
#define NB     16          // biquads
#define CHUNK  64
#define NCH    (S / CHUNK)     // 768 chunks = threads per block
#define NWAVE  (NCH / 64)      // 12 waves

__device__ __forceinline__ float clampf(float x, float lo, float hi) {
    return fminf(fmaxf(x, lo), hi);
}

// sc[f][fr][i]:
// 0:t00 1:t01 2:t10 3:t11 4:b0 5:b1 6:c0 7:c1 8:c2 9:M00 10:M01 11:M10 12:M11
//
// waves_per_eu(3,3): 768-thread block = 12 waves = 3 waves/EU, and only 32
// blocks exist for 256 CUs -> 1 block/CU max. Pinning min=max=3 grants the
// allocator the full ~168-VGPR budget so xr[64] stays in registers instead
// of spilling to scratch (R2: min-only bound left VGPR=84 + scratch spill,
// 2.8x regression).
__global__ __launch_bounds__(NCH)
__attribute__((amdgpu_waves_per_eu(3, 3)))
void biquad_chain_kernel(const float* __restrict__ audio,
                         const float* __restrict__ params,
                         float* __restrict__ out)
{
    __shared__ float sc[NB][NF][14];
    __shared__ float sgain[2][NF];      // [0]=in gain, [1]=out gain
    __shared__ float sagg[NWAVE][6];    // wave aggregates for the scan

    const int t    = threadIdx.x;
    const int b    = blockIdx.x;
    const int lane = t & 63;
    const int wave = t >> 6;

    // ---------------- coefficient init (threads 0..383) ----------------
    if (t < NB * NF) {
        const int f  = t / NF;
        const int fr = t % NF;
        const float* P = params + (size_t)b * 50 * NF;
        const float fn = P[(3 * f + 0) * NF + fr];
        const float gn = P[(3 * f + 1) * NF + fr];
        const float qn = P[(3 * f + 2) * NF + fr];

        // Q = exp(log .5 + qn*(log 16 - log .5))
        float Q = __expf(-0.69314718f + qn * 3.4657359f);
        Q = clampf(Q, 0.1f, 100.0f);

        float lo, hi;
        int type;                        // 0 hp, 1 lp, 2 peak, 3 lowshelf, 4 highshelf
        if      (f == 0)  { lo = 20.0f;   hi = 500.0f;   type = 0; }
        else if (f == 15) { lo = 5000.0f; hi = 20000.0f; type = 1; }
        else if (f == 1)  { lo = 50.0f;   hi = 16000.0f; type = 3; }
        else if (f == 14) { lo = 50.0f;   hi = 16000.0f; type = 4; }
        else              { lo = 100.0f;  hi = 15000.0f; type = 2; }

        const float fc = __expf(__logf(lo) + fn * (__logf(hi) - __logf(lo)));
        float g = __tanf((float)M_PI * fc / 96000.0f);   // angle <= 0.655 rad, safe
        g = clampf(g, 1e-6f, 100.0f);
        const float gdb = -24.0f + 48.0f * gn;

        float a1, a2, a3, m0, m1, m2;
        if (type == 0 || type == 1) {
            const float k = 1.0f / Q;
            a1 = 1.0f / (1.0f + g * (g + k)); a2 = g * a1; a3 = g * a2;
            if (type == 0) { m0 = 1.0f; m1 = -k;   m2 = -1.0f; }
            else           { m0 = 0.0f; m1 = 0.0f; m2 = 1.0f;  }
        } else if (type == 2) {
            const float A = __expf(gdb * (2.30258509f / 40.0f));
            const float k = (gdb >= 0.0f) ? 1.0f / (Q * A) : A / Q;
            a1 = 1.0f / (1.0f + g * (g + k)); a2 = g * a1; a3 = g * a2;
            m0 = 1.0f; m1 = k * (A * A - 1.0f); m2 = 0.0f;
        } else {
            const float A  = __expf(gdb * (2.30258509f / 40.0f));
            const float sA = sqrtf(A);
            const float k  = 1.0f / Q;
            float gs;
            if (type == 3) gs = (gdb >= 0.0f) ? g / sA : g * sA;
            else           gs = (gdb >= 0.0f) ? g * sA : g / sA;
            a1 = 1.0f / (1.0f + gs * (gs + k)); a2 = gs * a1; a3 = gs * a2;
            if (type == 3) { m0 = 1.0f;  m1 = k * (A - 1.0f);      m2 = A * A - 1.0f; }
            else           { m0 = A * A; m1 = k * (1.0f - A) * A;  m2 = 1.0f - A * A; }
        }

        // affine per-sample form: s' = T s + b*x ; y = c0*ic1 + c1*ic2 + c2*x
        const float q2  = a2 * a2 + a3;
        const float t00 = 2.0f * a1 - 1.0f;
        const float t01 = -2.0f * a2;
        const float t10 = 2.0f * a1 * a2;
        const float t11 = 1.0f - 2.0f * q2;
        const float b0  = 2.0f * a2;
        const float b1  = 2.0f * q2;
        const float c0  = a1 * (m1 + m2 * a2);
        const float c1  = m2 * (1.0f - q2) - m1 * a2;
        const float c2  = m0 + m1 * a2 + m2 * q2;

        // M = T^64 by 6 squarings
        float u00 = t00, u01 = t01, u10 = t10, u11 = t11;
        #pragma unroll
        for (int i = 0; i < 6; i++) {
            const float n00 = u00 * u00 + u01 * u10;
            const float n01 = u00 * u01 + u01 * u11;
            const float n10 = u10 * u00 + u11 * u10;
            const float n11 = u10 * u01 + u11 * u11;
            u00 = n00; u01 = n01; u10 = n10; u11 = n11;
        }

        sc[f][fr][0] = t00; sc[f][fr][1] = t01; sc[f][fr][2] = t10; sc[f][fr][3] = t11;
        sc[f][fr][4] = b0;  sc[f][fr][5] = b1;
        sc[f][fr][6] = c0;  sc[f][fr][7] = c1;  sc[f][fr][8] = c2;
        sc[f][fr][9] = u00; sc[f][fr][10] = u01; sc[f][fr][11] = u10; sc[f][fr][12] = u11;
    }
    if (t >= 384 && t < 384 + 2 * NF) {
        const int idx = t - 384;
        const int which = idx / NF;     // 0 = in gain (row 48), 1 = out gain (row 49)
        const int fr    = idx % NF;
        const float* P = params + (size_t)b * 50 * NF;
        const float p  = P[(48 + which) * NF + fr];
        const float db = -60.0f + 60.0f * p;
        sgain[which][fr] = __expf(db * (2.30258509f / 20.0f));
    }
    __syncthreads();

    // ---------------- load chunk (with input gain) ----------------
    const int frame = t >> 5;           // 32 chunks per frame
    const float ing = sgain[0][frame];
    float xr[CHUNK];
    {
        const float4* src = (const float4*)(audio + (size_t)b * S + (size_t)t * CHUNK);
        #pragma unroll
        for (int i = 0; i < CHUNK / 4; i++) {
            const float4 v = src[i];
            xr[4 * i + 0] = v.x * ing;
            xr[4 * i + 1] = v.y * ing;
            xr[4 * i + 2] = v.z * ing;
            xr[4 * i + 3] = v.w * ing;
        }
    }

    // ---------------- 16 cascaded stages ----------------
    #pragma unroll 1
    for (int f = 0; f < NB; f++) {
        const float t00 = sc[f][frame][0];
        const float t01 = sc[f][frame][1];
        const float t10 = sc[f][frame][2];
        const float t11 = sc[f][frame][3];
        const float b0  = sc[f][frame][4];
        const float b1  = sc[f][frame][5];
        const float c0  = sc[f][frame][6];
        const float c1  = sc[f][frame][7];
        const float c2  = sc[f][frame][8];
        const float M00 = sc[f][frame][9];
        const float M01 = sc[f][frame][10];
        const float M10 = sc[f][frame][11];
        const float M11 = sc[f][frame][12];

        // Phase A: zero-state run over own chunk -> affine constant c
        float ic1 = 0.0f, ic2 = 0.0f;
        #pragma unroll
        for (int n = 0; n < CHUNK; n++) {
            const float x  = xr[n];
            const float n1 = fmaf(t00, ic1, fmaf(t01, ic2, b0 * x));
            const float n2 = fmaf(t10, ic1, fmaf(t11, ic2, b1 * x));
            ic1 = n1; ic2 = n2;
        }

        // own affine map (A, Ac); wave-level inclusive scan via shfl_up
        float A00 = M00, A01 = M01, A10 = M10, A11 = M11;
        float Ac0 = ic1, Ac1 = ic2;
        #pragma unroll
        for (int d = 1; d < 64; d <<= 1) {
            const float l00 = __shfl_up(A00, d);
            const float l01 = __shfl_up(A01, d);
            const float l10 = __shfl_up(A10, d);
            const float l11 = __shfl_up(A11, d);
            const float lc0 = __shfl_up(Ac0, d);
            const float lc1 = __shfl_up(Ac1, d);
            if (lane >= d) {
                const float n00 = A00 * l00 + A01 * l10;
                const float n01 = A00 * l01 + A01 * l11;
                const float n10 = A10 * l00 + A11 * l10;
                const float n11 = A10 * l01 + A11 * l11;
                const float nc0 = A00 * lc0 + A01 * lc1 + Ac0;
                const float nc1 = A10 * lc0 + A11 * lc1 + Ac1;
                A00 = n00; A01 = n01; A10 = n10; A11 = n11;
                Ac0 = nc0; Ac1 = nc1;
            }
        }

        __syncthreads();   // protect sagg reuse from previous stage
        if (lane == 63) {
            sagg[wave][0] = A00; sagg[wave][1] = A01;
            sagg[wave][2] = A10; sagg[wave][3] = A11;
            sagg[wave][4] = Ac0; sagg[wave][5] = Ac1;
        }
        __syncthreads();

        // wave prefix = compose aggregates of waves 0..wave-1 (in order)
        float W00 = 1.0f, W01 = 0.0f, W10 = 0.0f, W11 = 1.0f, Wc0 = 0.0f, Wc1 = 0.0f;
        for (int k2 = 0; k2 < wave; k2++) {
            const float g00 = sagg[k2][0], g01 = sagg[k2][1];
            const float g10 = sagg[k2][2], g11 = sagg[k2][3];
            const float gc0 = sagg[k2][4], gc1 = sagg[k2][5];
            const float n00 = g00 * W00 + g01 * W10;
            const float n01 = g00 * W01 + g01 * W11;
            const float n10 = g10 * W00 + g11 * W10;
            const float n11 = g10 * W01 + g11 * W11;
            const float nc0 = g00 * Wc0 + g01 * Wc1 + gc0;
            const float nc1 = g10 * Wc0 + g11 * Wc1 + gc1;
            W00 = n00; W01 = n01; W10 = n10; W11 = n11;
            Wc0 = nc0; Wc1 = nc1;
        }

        // incoming state = exclusive prefix applied to zero initial state
        const float P00 = __shfl_up(A00, 1);
        const float P01 = __shfl_up(A01, 1);
        const float P10 = __shfl_up(A10, 1);
        const float P11 = __shfl_up(A11, 1);
        const float Pc0 = __shfl_up(Ac0, 1);
        const float Pc1 = __shfl_up(Ac1, 1);
        float s0, s1;
        if (lane == 0) { s0 = Wc0; s1 = Wc1; }
        else {
            s0 = P00 * Wc0 + P01 * Wc1 + Pc0;
            s1 = P10 * Wc0 + P11 * Wc1 + Pc1;
        }

        // Phase C: true run from incoming state, write outputs in place
        ic1 = s0; ic2 = s1;
        #pragma unroll
        for (int n = 0; n < CHUNK; n++) {
            const float x  = xr[n];
            const float y  = fmaf(c0, ic1, fmaf(c1, ic2, c2 * x));
            const float n1 = fmaf(t00, ic1, fmaf(t01, ic2, b0 * x));
            const float n2 = fmaf(t10, ic1, fmaf(t11, ic2, b1 * x));
            xr[n] = y;
            ic1 = n1; ic2 = n2;
        }
    }

    // ---------------- store (with output gain) ----------------
    {
        const float og = sgain[1][frame];
        float4* dst = (float4*)(out + (size_t)b * S + (size_t)t * CHUNK);
        #pragma unroll
        for (int i = 0; i < CHUNK / 4; i++) {
            float4 v;
            v.x = xr[4 * i + 0] * og;
            v.y = xr[4 * i + 1] * og;
            v.z = xr[4 * i + 2] * og;
            v.w = xr[4 * i + 3] * og;
            dst[i] = v;
        }
    }
}

extern "C" void kernel_launch(void* const* d_in, const int* in_sizes, int n_in,
                              void* d_out, int out_size, void* d_ws, size_t ws_size,
                              hipStream_t stream)
{
    const float* audio  = (const float*)d_in[0];
    const float* params = (const float*)d_in[1];
    float* out = (float*)d_out;
    biquad_chain_kernel<<<NBATCH, NCH, 0, stream>>>(audio, params, out);
}

// Round 4
// 247.635 us; speedup vs baseline: 1.6213x; 1.6213x over previous
//
#include <hip/hip_runtime.h>
#include <math.h>

#define NBATCH 32
#define S      49152
#define NF     24          // frames
#define NB     16          // biquads
#define CHUNK  64
#define NCH    (S / CHUNK)     // 768 chunks = threads per block
#define NWAVE  (NCH / 64)      // 12 waves

typedef float v16f __attribute__((ext_vector_type(16)));

__device__ __forceinline__ float clampf(float x, float lo, float hi) {
    return fminf(fmaxf(x, lo), hi);
}

// Signal lives in 4x <16 x float> SSA vectors (64 VGPRs) -- NOT an alloca.
// R1-R3 post-mortem: float xr[64] was never promoted out of scratch
// (VGPR_Count pinned at 84 across launch_bounds/waves_per_eu variants);
// ext_vector values can't be allocas, so they must be register-allocated.
// waves_per_eu(3,3): block is 12 waves = 3/EU (1 block/CU); budget 512/3=170.
__global__
__attribute__((amdgpu_flat_work_group_size(NCH, NCH), amdgpu_waves_per_eu(3, 3)))
void biquad_chain_kernel(const float* __restrict__ audio,
                         const float* __restrict__ params,
                         float* __restrict__ out)
{
    __shared__ float sc[NB][NF][14];
    __shared__ float sgain[2][NF];      // [0]=in gain, [1]=out gain
    __shared__ float sagg[NWAVE][6];    // wave aggregates for the scan

    const int t    = threadIdx.x;
    const int b    = blockIdx.x;
    const int lane = t & 63;
    const int wave = t >> 6;

    // ---------------- coefficient init (threads 0..383) ----------------
    if (t < NB * NF) {
        const int f  = t / NF;
        const int fr = t % NF;
        const float* P = params + (size_t)b * 50 * NF;
        const float fn = P[(3 * f + 0) * NF + fr];
        const float gn = P[(3 * f + 1) * NF + fr];
        const float qn = P[(3 * f + 2) * NF + fr];

        float Q = __expf(-0.69314718f + qn * 3.4657359f);
        Q = clampf(Q, 0.1f, 100.0f);

        float lo, hi;
        int type;                        // 0 hp, 1 lp, 2 peak, 3 lowshelf, 4 highshelf
        if      (f == 0)  { lo = 20.0f;   hi = 500.0f;   type = 0; }
        else if (f == 15) { lo = 5000.0f; hi = 20000.0f; type = 1; }
        else if (f == 1)  { lo = 50.0f;   hi = 16000.0f; type = 3; }
        else if (f == 14) { lo = 50.0f;   hi = 16000.0f; type = 4; }
        else              { lo = 100.0f;  hi = 15000.0f; type = 2; }

        const float fc = __expf(__logf(lo) + fn * (__logf(hi) - __logf(lo)));
        float g = __tanf((float)M_PI * fc / 96000.0f);   // angle <= 0.655 rad, safe
        g = clampf(g, 1e-6f, 100.0f);
        const float gdb = -24.0f + 48.0f * gn;

        float a1, a2, a3, m0, m1, m2;
        if (type == 0 || type == 1) {
            const float k = 1.0f / Q;
            a1 = 1.0f / (1.0f + g * (g + k)); a2 = g * a1; a3 = g * a2;
            if (type == 0) { m0 = 1.0f; m1 = -k;   m2 = -1.0f; }
            else           { m0 = 0.0f; m1 = 0.0f; m2 = 1.0f;  }
        } else if (type == 2) {
            const float A = __expf(gdb * (2.30258509f / 40.0f));
            const float k = (gdb >= 0.0f) ? 1.0f / (Q * A) : A / Q;
            a1 = 1.0f / (1.0f + g * (g + k)); a2 = g * a1; a3 = g * a2;
            m0 = 1.0f; m1 = k * (A * A - 1.0f); m2 = 0.0f;
        } else {
            const float A  = __expf(gdb * (2.30258509f / 40.0f));
            const float sA = sqrtf(A);
            const float k  = 1.0f / Q;
            float gs;
            if (type == 3) gs = (gdb >= 0.0f) ? g / sA : g * sA;
            else           gs = (gdb >= 0.0f) ? g * sA : g / sA;
            a1 = 1.0f / (1.0f + gs * (gs + k)); a2 = gs * a1; a3 = gs * a2;
            if (type == 3) { m0 = 1.0f;  m1 = k * (A - 1.0f);      m2 = A * A - 1.0f; }
            else           { m0 = A * A; m1 = k * (1.0f - A) * A;  m2 = 1.0f - A * A; }
        }

        // affine per-sample form: s' = T s + b*x ; y = c0*ic1 + c1*ic2 + c2*x
        const float q2  = a2 * a2 + a3;
        const float t00 = 2.0f * a1 - 1.0f;
        const float t01 = -2.0f * a2;
        const float t10 = 2.0f * a1 * a2;
        const float t11 = 1.0f - 2.0f * q2;
        const float b0  = 2.0f * a2;
        const float b1  = 2.0f * q2;
        const float c0  = a1 * (m1 + m2 * a2);
        const float c1  = m2 * (1.0f - q2) - m1 * a2;
        const float c2  = m0 + m1 * a2 + m2 * q2;

        // M = T^64 by 6 squarings
        float u00 = t00, u01 = t01, u10 = t10, u11 = t11;
        #pragma unroll
        for (int i = 0; i < 6; i++) {
            const float n00 = u00 * u00 + u01 * u10;
            const float n01 = u00 * u01 + u01 * u11;
            const float n10 = u10 * u00 + u11 * u10;
            const float n11 = u10 * u01 + u11 * u11;
            u00 = n00; u01 = n01; u10 = n10; u11 = n11;
        }

        sc[f][fr][0] = t00; sc[f][fr][1] = t01; sc[f][fr][2] = t10; sc[f][fr][3] = t11;
        sc[f][fr][4] = b0;  sc[f][fr][5] = b1;
        sc[f][fr][6] = c0;  sc[f][fr][7] = c1;  sc[f][fr][8] = c2;
        sc[f][fr][9] = u00; sc[f][fr][10] = u01; sc[f][fr][11] = u10; sc[f][fr][12] = u11;
    }
    if (t >= 384 && t < 384 + 2 * NF) {
        const int idx = t - 384;
        const int which = idx / NF;     // 0 = in gain (row 48), 1 = out gain (row 49)
        const int fr    = idx % NF;
        const float* P = params + (size_t)b * 50 * NF;
        const float p  = P[(48 + which) * NF + fr];
        const float db = -60.0f + 60.0f * p;
        sgain[which][fr] = __expf(db * (2.30258509f / 20.0f));
    }
    __syncthreads();

    // ---------------- load chunk (with input gain) ----------------
    const int frame = t >> 5;           // 32 chunks per frame
    const float ing = sgain[0][frame];
    v16f xv[4];                          // 4-elem array of SSA vectors; SROA splits it
    {
        const v16f* src = (const v16f*)(audio + (size_t)b * S + (size_t)t * CHUNK);
        #pragma unroll
        for (int j = 0; j < 4; j++) xv[j] = src[j] * ing;
    }

    // ---------------- 16 cascaded stages ----------------
    #pragma unroll 1
    for (int f = 0; f < NB; f++) {
        const float t00 = sc[f][frame][0];
        const float t01 = sc[f][frame][1];
        const float t10 = sc[f][frame][2];
        const float t11 = sc[f][frame][3];
        const float b0  = sc[f][frame][4];
        const float b1  = sc[f][frame][5];
        const float c0  = sc[f][frame][6];
        const float c1  = sc[f][frame][7];
        const float c2  = sc[f][frame][8];
        const float M00 = sc[f][frame][9];
        const float M01 = sc[f][frame][10];
        const float M10 = sc[f][frame][11];
        const float M11 = sc[f][frame][12];

        // Phase A: zero-state run over own chunk -> affine constant c
        float ic1 = 0.0f, ic2 = 0.0f;
        #pragma unroll
        for (int j = 0; j < 4; j++) {
            #pragma unroll
            for (int n = 0; n < 16; n++) {
                const float x  = xv[j][n];
                const float n1 = fmaf(t00, ic1, fmaf(t01, ic2, b0 * x));
                const float n2 = fmaf(t10, ic1, fmaf(t11, ic2, b1 * x));
                ic1 = n1; ic2 = n2;
            }
        }

        // own affine map (A, Ac); wave-level inclusive scan via shfl_up
        float A00 = M00, A01 = M01, A10 = M10, A11 = M11;
        float Ac0 = ic1, Ac1 = ic2;
        #pragma unroll
        for (int d = 1; d < 64; d <<= 1) {
            const float l00 = __shfl_up(A00, d);
            const float l01 = __shfl_up(A01, d);
            const float l10 = __shfl_up(A10, d);
            const float l11 = __shfl_up(A11, d);
            const float lc0 = __shfl_up(Ac0, d);
            const float lc1 = __shfl_up(Ac1, d);
            if (lane >= d) {
                const float n00 = A00 * l00 + A01 * l10;
                const float n01 = A00 * l01 + A01 * l11;
                const float n10 = A10 * l00 + A11 * l10;
                const float n11 = A10 * l01 + A11 * l11;
                const float nc0 = A00 * lc0 + A01 * lc1 + Ac0;
                const float nc1 = A10 * lc0 + A11 * lc1 + Ac1;
                A00 = n00; A01 = n01; A10 = n10; A11 = n11;
                Ac0 = nc0; Ac1 = nc1;
            }
        }

        __syncthreads();   // protect sagg reuse from previous stage
        if (lane == 63) {
            sagg[wave][0] = A00; sagg[wave][1] = A01;
            sagg[wave][2] = A10; sagg[wave][3] = A11;
            sagg[wave][4] = Ac0; sagg[wave][5] = Ac1;
        }
        __syncthreads();

        // wave prefix = compose aggregates of waves 0..wave-1 (in order)
        float W00 = 1.0f, W01 = 0.0f, W10 = 0.0f, W11 = 1.0f, Wc0 = 0.0f, Wc1 = 0.0f;
        for (int k2 = 0; k2 < wave; k2++) {
            const float g00 = sagg[k2][0], g01 = sagg[k2][1];
            const float g10 = sagg[k2][2], g11 = sagg[k2][3];
            const float gc0 = sagg[k2][4], gc1 = sagg[k2][5];
            const float n00 = g00 * W00 + g01 * W10;
            const float n01 = g00 * W01 + g01 * W11;
            const float n10 = g10 * W00 + g11 * W10;
            const float n11 = g10 * W01 + g11 * W11;
            const float nc0 = g00 * Wc0 + g01 * Wc1 + gc0;
            const float nc1 = g10 * Wc0 + g11 * Wc1 + gc1;
            W00 = n00; W01 = n01; W10 = n10; W11 = n11;
            Wc0 = nc0; Wc1 = nc1;
        }

        // incoming state = exclusive prefix applied to zero initial state
        const float P00 = __shfl_up(A00, 1);
        const float P01 = __shfl_up(A01, 1);
        const float P10 = __shfl_up(A10, 1);
        const float P11 = __shfl_up(A11, 1);
        const float Pc0 = __shfl_up(Ac0, 1);
        const float Pc1 = __shfl_up(Ac1, 1);
        float s0, s1;
        if (lane == 0) { s0 = Wc0; s1 = Wc1; }
        else {
            s0 = P00 * Wc0 + P01 * Wc1 + Pc0;
            s1 = P10 * Wc0 + P11 * Wc1 + Pc1;
        }

        // Phase C: true run from incoming state, write outputs in place
        ic1 = s0; ic2 = s1;
        #pragma unroll
        for (int j = 0; j < 4; j++) {
            #pragma unroll
            for (int n = 0; n < 16; n++) {
                const float x  = xv[j][n];
                const float y  = fmaf(c0, ic1, fmaf(c1, ic2, c2 * x));
                const float n1 = fmaf(t00, ic1, fmaf(t01, ic2, b0 * x));
                const float n2 = fmaf(t10, ic1, fmaf(t11, ic2, b1 * x));
                xv[j][n] = y;
                ic1 = n1; ic2 = n2;
            }
        }
    }

    // ---------------- store (with output gain) ----------------
    {
        const float og = sgain[1][frame];
        v16f* dst = (v16f*)(out + (size_t)b * S + (size_t)t * CHUNK);
        #pragma unroll
        for (int j = 0; j < 4; j++) dst[j] = xv[j] * og;
    }
}

extern "C" void kernel_launch(void* const* d_in, const int* in_sizes, int n_in,
                              void* d_out, int out_size, void* d_ws, size_t ws_size,
                              hipStream_t stream)
{
    const float* audio  = (const float*)d_in[0];
    const float* params = (const float*)d_in[1];
    float* out = (float*)d_out;
    biquad_chain_kernel<<<NBATCH, NCH, 0, stream>>>(audio, params, out);
}

// Round 6
// 137.776 us; speedup vs baseline: 2.9142x; 1.7974x over previous
//
#include <hip/hip_runtime.h>
#include <math.h>

#define NBATCH 32
#define S      49152
#define NF     24          // frames (2048 samples each)
#define NB     16          // biquads
#define CHUNK  32          // samples per thread
#define NCH    768         // threads per block
#define NWAVE  12          // waves per block
// 2 blocks per batch; block covers 768*32 = 24576 samples = 12 frames.

__device__ __forceinline__ float clampf(float x, float lo, float hi) {
    return fminf(fmaxf(x, lo), hi);
}

// 32 named scalar signal registers -- guaranteed SSA (no alloca).
#define FOREACH_S(OP) \
    OP(s00) OP(s01) OP(s02) OP(s03) OP(s04) OP(s05) OP(s06) OP(s07) \
    OP(s08) OP(s09) OP(s10) OP(s11) OP(s12) OP(s13) OP(s14) OP(s15) \
    OP(s16) OP(s17) OP(s18) OP(s19) OP(s20) OP(s21) OP(s22) OP(s23) \
    OP(s24) OP(s25) OP(s26) OP(s27) OP(s28) OP(s29) OP(s30) OP(s31)

#define DECL_S(x) float x;

// Phase A step: state only.  s' = T s + b*x
#define STEPA(x) { \
    const float n1_ = fmaf(t00, ic1, fmaf(t01, ic2, b0 * (x))); \
    const float n2_ = fmaf(t10, ic1, fmaf(t11, ic2, b1 * (x))); \
    ic1 = n1_; ic2 = n2_; }

// Phase C step: output + state.  y = c0*ic1 + c1*ic2 + c2*x, in place.
#define STEPC(x) { \
    const float y_  = fmaf(c0, ic1, fmaf(c1, ic2, c2 * (x))); \
    const float n1_ = fmaf(t00, ic1, fmaf(t01, ic2, b0 * (x))); \
    const float n2_ = fmaf(t10, ic1, fmaf(t11, ic2, b1 * (x))); \
    (x) = y_; ic1 = n1_; ic2 = n2_; }

// R1-R4: allocator pins VGPR at 84 regardless of occupancy hints; any demand
// above spills to scratch. So demand must fit 84: 32 named scalars + ~40 rest.
// R5 post-mortem: single flag slot deadlocked (producer overwrites tag f+1
// with f+2 before consumer reads it). Fix: one write-once slot per stage.
__global__ __launch_bounds__(NCH, 3)
void biquad_chain_kernel(const float* __restrict__ audio,
                         const float* __restrict__ params,
                         float* __restrict__ out,
                         unsigned int* __restrict__ ws)
{
    __shared__ float sc[NB][NF][14];
    __shared__ float sgain[2][NF];      // [0]=in gain, [1]=out gain
    __shared__ float sagg[NWAVE][6];    // wave aggregates for the scan
    __shared__ float sS0[2];            // broadcast of incoming half-state

    const int t    = threadIdx.x;
    const int bt   = blockIdx.x >> 1;   // batch
    const int half = blockIdx.x & 1;    // 0: samples [0,24576), 1: [24576,49152)
    const int lane = t & 63;
    const int wave = t >> 6;
    const int g    = half * NCH + t;    // global chunk index in batch [0,1536)
    const int frame = half * 12 + wave; // 64 chunks (1 wave) per 2048-frame

    // handshake: per (batch, stage) write-once slot {flag, d0, d1, pad} u32.
    // 32*16*4 u32 = 8 KB of d_ws. tag=f+1 never equals 0xAAAAAAAA poison.
    unsigned int* slotbase = ws + 4 * (bt * NB);

    // ---------------- coefficient init (threads 0..383) ----------------
    if (t < NB * NF) {
        const int f  = t / NF;
        const int fr = t % NF;
        const float* P = params + (size_t)bt * 50 * NF;
        const float fn = P[(3 * f + 0) * NF + fr];
        const float gn = P[(3 * f + 1) * NF + fr];
        const float qn = P[(3 * f + 2) * NF + fr];

        float Q = __expf(-0.69314718f + qn * 3.4657359f);
        Q = clampf(Q, 0.1f, 100.0f);

        float lo, hi;
        int type;                        // 0 hp, 1 lp, 2 peak, 3 lowshelf, 4 highshelf
        if      (f == 0)  { lo = 20.0f;   hi = 500.0f;   type = 0; }
        else if (f == 15) { lo = 5000.0f; hi = 20000.0f; type = 1; }
        else if (f == 1)  { lo = 50.0f;   hi = 16000.0f; type = 3; }
        else if (f == 14) { lo = 50.0f;   hi = 16000.0f; type = 4; }
        else              { lo = 100.0f;  hi = 15000.0f; type = 2; }

        const float fc = __expf(__logf(lo) + fn * (__logf(hi) - __logf(lo)));
        float g_ = __tanf((float)M_PI * fc / 96000.0f);   // angle <= 0.655 rad, safe
        g_ = clampf(g_, 1e-6f, 100.0f);
        const float gdb = -24.0f + 48.0f * gn;

        float a1, a2, a3, m0, m1, m2;
        if (type == 0 || type == 1) {
            const float k = 1.0f / Q;
            a1 = 1.0f / (1.0f + g_ * (g_ + k)); a2 = g_ * a1; a3 = g_ * a2;
            if (type == 0) { m0 = 1.0f; m1 = -k;   m2 = -1.0f; }
            else           { m0 = 0.0f; m1 = 0.0f; m2 = 1.0f;  }
        } else if (type == 2) {
            const float A = __expf(gdb * (2.30258509f / 40.0f));
            const float k = (gdb >= 0.0f) ? 1.0f / (Q * A) : A / Q;
            a1 = 1.0f / (1.0f + g_ * (g_ + k)); a2 = g_ * a1; a3 = g_ * a2;
            m0 = 1.0f; m1 = k * (A * A - 1.0f); m2 = 0.0f;
        } else {
            const float A  = __expf(gdb * (2.30258509f / 40.0f));
            const float sA = sqrtf(A);
            const float k  = 1.0f / Q;
            float gs;
            if (type == 3) gs = (gdb >= 0.0f) ? g_ / sA : g_ * sA;
            else           gs = (gdb >= 0.0f) ? g_ * sA : g_ / sA;
            a1 = 1.0f / (1.0f + gs * (gs + k)); a2 = gs * a1; a3 = gs * a2;
            if (type == 3) { m0 = 1.0f;  m1 = k * (A - 1.0f);      m2 = A * A - 1.0f; }
            else           { m0 = A * A; m1 = k * (1.0f - A) * A;  m2 = 1.0f - A * A; }
        }

        // affine per-sample form: s' = T s + b*x ; y = c0*ic1 + c1*ic2 + c2*x
        const float q2  = a2 * a2 + a3;
        const float t00 = 2.0f * a1 - 1.0f;
        const float t01 = -2.0f * a2;
        const float t10 = 2.0f * a1 * a2;
        const float t11 = 1.0f - 2.0f * q2;
        const float b0  = 2.0f * a2;
        const float b1  = 2.0f * q2;
        const float c0  = a1 * (m1 + m2 * a2);
        const float c1  = m2 * (1.0f - q2) - m1 * a2;
        const float c2  = m0 + m1 * a2 + m2 * q2;

        // M = T^32 by 5 squarings
        float u00 = t00, u01 = t01, u10 = t10, u11 = t11;
        #pragma unroll
        for (int i = 0; i < 5; i++) {
            const float n00 = u00 * u00 + u01 * u10;
            const float n01 = u00 * u01 + u01 * u11;
            const float n10 = u10 * u00 + u11 * u10;
            const float n11 = u10 * u01 + u11 * u11;
            u00 = n00; u01 = n01; u10 = n10; u11 = n11;
        }

        sc[f][fr][0] = t00; sc[f][fr][1] = t01; sc[f][fr][2] = t10; sc[f][fr][3] = t11;
        sc[f][fr][4] = b0;  sc[f][fr][5] = b1;
        sc[f][fr][6] = c0;  sc[f][fr][7] = c1;  sc[f][fr][8] = c2;
        sc[f][fr][9] = u00; sc[f][fr][10] = u01; sc[f][fr][11] = u10; sc[f][fr][12] = u11;
    }
    if (t >= 384 && t < 384 + 2 * NF) {
        const int idx = t - 384;
        const int which = idx / NF;     // 0 = in gain (row 48), 1 = out gain (row 49)
        const int fr    = idx % NF;
        const float* P = params + (size_t)bt * 50 * NF;
        const float p  = P[(48 + which) * NF + fr];
        const float db = -60.0f + 60.0f * p;
        sgain[which][fr] = __expf(db * (2.30258509f / 20.0f));
    }
    __syncthreads();

    // ---------------- load chunk (with input gain) ----------------
    FOREACH_S(DECL_S)
    {
        const float ing = sgain[0][frame];
        const float* base = audio + (size_t)bt * S + (size_t)g * CHUNK;
        float4 q;
        q = *(const float4*)(base +  0); s00 = q.x*ing; s01 = q.y*ing; s02 = q.z*ing; s03 = q.w*ing;
        q = *(const float4*)(base +  4); s04 = q.x*ing; s05 = q.y*ing; s06 = q.z*ing; s07 = q.w*ing;
        q = *(const float4*)(base +  8); s08 = q.x*ing; s09 = q.y*ing; s10 = q.z*ing; s11 = q.w*ing;
        q = *(const float4*)(base + 12); s12 = q.x*ing; s13 = q.y*ing; s14 = q.z*ing; s15 = q.w*ing;
        q = *(const float4*)(base + 16); s16 = q.x*ing; s17 = q.y*ing; s18 = q.z*ing; s19 = q.w*ing;
        q = *(const float4*)(base + 20); s20 = q.x*ing; s21 = q.y*ing; s22 = q.z*ing; s23 = q.w*ing;
        q = *(const float4*)(base + 24); s24 = q.x*ing; s25 = q.y*ing; s26 = q.z*ing; s27 = q.w*ing;
        q = *(const float4*)(base + 28); s28 = q.x*ing; s29 = q.y*ing; s30 = q.z*ing; s31 = q.w*ing;
    }

    // ---------------- 16 cascaded stages ----------------
    #pragma unroll 1
    for (int f = 0; f < NB; f++) {
        const float t00 = sc[f][frame][0];
        const float t01 = sc[f][frame][1];
        const float t10 = sc[f][frame][2];
        const float t11 = sc[f][frame][3];
        const float b0  = sc[f][frame][4];
        const float b1  = sc[f][frame][5];
        const float c0  = sc[f][frame][6];
        const float c1  = sc[f][frame][7];
        const float c2  = sc[f][frame][8];

        // Phase A: zero-state run over own chunk -> affine constant
        float ic1 = 0.0f, ic2 = 0.0f;
        FOREACH_S(STEPA)

        // own affine map (A = T^32 from LDS, Ac = phase-A constant)
        float A00 = sc[f][frame][9];
        float A01 = sc[f][frame][10];
        float A10 = sc[f][frame][11];
        float A11 = sc[f][frame][12];
        float Ac0 = ic1, Ac1 = ic2;
        #pragma unroll
        for (int d = 1; d < 64; d <<= 1) {
            const float l00 = __shfl_up(A00, d);
            const float l01 = __shfl_up(A01, d);
            const float l10 = __shfl_up(A10, d);
            const float l11 = __shfl_up(A11, d);
            const float lc0 = __shfl_up(Ac0, d);
            const float lc1 = __shfl_up(Ac1, d);
            if (lane >= d) {
                const float n00 = A00 * l00 + A01 * l10;
                const float n01 = A00 * l01 + A01 * l11;
                const float n10 = A10 * l00 + A11 * l10;
                const float n11 = A10 * l01 + A11 * l11;
                const float nc0 = A00 * lc0 + A01 * lc1 + Ac0;
                const float nc1 = A10 * lc0 + A11 * lc1 + Ac1;
                A00 = n00; A01 = n01; A10 = n10; A11 = n11;
                Ac0 = nc0; Ac1 = nc1;
            }
        }

        __syncthreads();   // protect sagg/sS0 reuse from previous stage
        if (lane == 63) {
            sagg[wave][0] = A00; sagg[wave][1] = A01;
            sagg[wave][2] = A10; sagg[wave][3] = A11;
            sagg[wave][4] = Ac0; sagg[wave][5] = Ac1;
        }
        __syncthreads();

        // wave prefix = compose aggregates of waves 0..wave-1 (in order)
        float W00 = 1.0f, W01 = 0.0f, W10 = 0.0f, W11 = 1.0f, Wc0 = 0.0f, Wc1 = 0.0f;
        for (int k2 = 0; k2 < wave; k2++) {
            const float g00 = sagg[k2][0], g01 = sagg[k2][1];
            const float g10 = sagg[k2][2], g11 = sagg[k2][3];
            const float gc0 = sagg[k2][4], gc1 = sagg[k2][5];
            const float n00 = g00 * W00 + g01 * W10;
            const float n01 = g00 * W01 + g01 * W11;
            const float n10 = g10 * W00 + g11 * W10;
            const float n11 = g10 * W01 + g11 * W11;
            const float nc0 = g00 * Wc0 + g01 * Wc1 + gc0;
            const float nc1 = g10 * Wc0 + g11 * Wc1 + gc1;
            W00 = n00; W01 = n01; W10 = n10; W11 = n11;
            Wc0 = nc0; Wc1 = nc1;
        }

        const unsigned int tag = (unsigned int)(f + 1);
        unsigned int* slot = slotbase + 4 * f;    // write-once per stage

        // block 0 (half 0): publish outgoing half-state for this stage
        if (half == 0) {
            if (t == NCH - 1) {
                const float e0 = A00 * Wc0 + A01 * Wc1 + Ac0;
                const float e1 = A10 * Wc0 + A11 * Wc1 + Ac1;
                float* datap = (float*)(slot + 1);
                __hip_atomic_store(&datap[0], e0, __ATOMIC_RELAXED, __HIP_MEMORY_SCOPE_AGENT);
                __hip_atomic_store(&datap[1], e1, __ATOMIC_RELAXED, __HIP_MEMORY_SCOPE_AGENT);
                __hip_atomic_store(slot, tag, __ATOMIC_RELEASE, __HIP_MEMORY_SCOPE_AGENT);
            }
        }

        // incoming state S0 for this half
        float S0x = 0.0f, S0y = 0.0f;
        if (half == 1) {
            // single spinner per block; broadcast via LDS (branch is
            // block-uniform, so the barrier is legal)
            if (t == 0) {
                while (__hip_atomic_load(slot, __ATOMIC_ACQUIRE, __HIP_MEMORY_SCOPE_AGENT) != tag) {
                    __builtin_amdgcn_s_sleep(2);
                }
                float* datap = (float*)(slot + 1);
                sS0[0] = __hip_atomic_load(&datap[0], __ATOMIC_RELAXED, __HIP_MEMORY_SCOPE_AGENT);
                sS0[1] = __hip_atomic_load(&datap[1], __ATOMIC_RELAXED, __HIP_MEMORY_SCOPE_AGENT);
            }
            __syncthreads();
            S0x = sS0[0];
            S0y = sS0[1];
        }

        // exclusive prefix affine E = (P ∘ W); incoming s = E.M * S0 + E.c
        float P00 = __shfl_up(A00, 1);
        float P01 = __shfl_up(A01, 1);
        float P10 = __shfl_up(A10, 1);
        float P11 = __shfl_up(A11, 1);
        float Pc0 = __shfl_up(Ac0, 1);
        float Pc1 = __shfl_up(Ac1, 1);
        if (lane == 0) { P00 = 1.0f; P01 = 0.0f; P10 = 0.0f; P11 = 1.0f; Pc0 = 0.0f; Pc1 = 0.0f; }
        const float E00 = P00 * W00 + P01 * W10;
        const float E01 = P00 * W01 + P01 * W11;
        const float E10 = P10 * W00 + P11 * W10;
        const float E11 = P10 * W01 + P11 * W11;
        const float Ec0 = P00 * Wc0 + P01 * Wc1 + Pc0;
        const float Ec1 = P10 * Wc0 + P11 * Wc1 + Pc1;

        // Phase C: true run from incoming state, write outputs in place
        ic1 = E00 * S0x + E01 * S0y + Ec0;
        ic2 = E10 * S0x + E11 * S0y + Ec1;
        FOREACH_S(STEPC)
    }

    // ---------------- store (with output gain) ----------------
    {
        const float og = sgain[1][frame];
        float* base = out + (size_t)bt * S + (size_t)g * CHUNK;
        float4 q;
        q.x = s00*og; q.y = s01*og; q.z = s02*og; q.w = s03*og; *(float4*)(base +  0) = q;
        q.x = s04*og; q.y = s05*og; q.z = s06*og; q.w = s07*og; *(float4*)(base +  4) = q;
        q.x = s08*og; q.y = s09*og; q.z = s10*og; q.w = s11*og; *(float4*)(base +  8) = q;
        q.x = s12*og; q.y = s13*og; q.z = s14*og; q.w = s15*og; *(float4*)(base + 12) = q;
        q.x = s16*og; q.y = s17*og; q.z = s18*og; q.w = s19*og; *(float4*)(base + 16) = q;
        q.x = s20*og; q.y = s21*og; q.z = s22*og; q.w = s23*og; *(float4*)(base + 20) = q;
        q.x = s24*og; q.y = s25*og; q.z = s26*og; q.w = s27*og; *(float4*)(base + 24) = q;
        q.x = s28*og; q.y = s29*og; q.z = s30*og; q.w = s31*og; *(float4*)(base + 28) = q;
    }
}

extern "C" void kernel_launch(void* const* d_in, const int* in_sizes, int n_in,
                              void* d_out, int out_size, void* d_ws, size_t ws_size,
                              hipStream_t stream)
{
    const float* audio  = (const float*)d_in[0];
    const float* params = (const float*)d_in[1];
    float* out = (float*)d_out;
    unsigned int* ws = (unsigned int*)d_ws;
    biquad_chain_kernel<<<2 * NBATCH, NCH, 0, stream>>>(audio, params, out, ws);
}

// Round 7
// 137.228 us; speedup vs baseline: 2.9258x; 1.0040x over previous
//
#include <hip/hip_runtime.h>
#include <math.h>

#define NBATCH 32
#define S      49152
#define NF     24          // frames (2048 samples each)
#define NB     16          // biquads
#define NBLK   4           // blocks per batch
#define CHUNK  16          // samples per thread
#define NCH    768         // threads per block
#define NWAVE  12          // waves per block
// 4 blocks per batch; block covers 768*16 = 12288 samples = 6 frames.

__device__ __forceinline__ float clampf(float x, float lo, float hi) {
    return fminf(fmaxf(x, lo), hi);
}

// 16 named scalar signal registers -- guaranteed SSA (no alloca; R1-R4 showed
// the allocator pins VGPR at 84 and spills float arrays regardless of hints).
#define FOREACH_S(OP) \
    OP(s00) OP(s01) OP(s02) OP(s03) OP(s04) OP(s05) OP(s06) OP(s07) \
    OP(s08) OP(s09) OP(s10) OP(s11) OP(s12) OP(s13) OP(s14) OP(s15)

#define DECL_S(x) float x;

// Phase A step: state only.  s' = T s + b*x
#define STEPA(x) { \
    const float n1_ = fmaf(t00, ic1, fmaf(t01, ic2, b0 * (x))); \
    const float n2_ = fmaf(t10, ic1, fmaf(t11, ic2, b1 * (x))); \
    ic1 = n1_; ic2 = n2_; }

// Phase C step: output + state.  y = c0*ic1 + c1*ic2 + c2*x, in place.
#define STEPC(x) { \
    const float y_  = fmaf(c0, ic1, fmaf(c1, ic2, c2 * (x))); \
    const float n1_ = fmaf(t00, ic1, fmaf(t01, ic2, b0 * (x))); \
    const float n2_ = fmaf(t10, ic1, fmaf(t11, ic2, b1 * (x))); \
    (x) = y_; ic1 = n1_; ic2 = n2_; }

// Cross-block protocol (R6-proven, generalized): per (batch,stage,block)
// write-once slot {flag, M00,M01,M10,M11, c0,c1, pad} u32[8]. Block j
// publishes its OWN aggregate affine map (independent of incoming state,
// so no serial chain between blocks) and spins on blocks 0..j-1. tag=f+1
// never equals the 0xAAAAAAAA ws poison. Producers never wait on consumers
// -> no deadlock regardless of scheduling. 32*16*4*8*4B = 64 KB of d_ws.
__global__ __launch_bounds__(NCH, 3)
void biquad_chain_kernel(const float* __restrict__ audio,
                         const float* __restrict__ params,
                         float* __restrict__ out,
                         unsigned int* __restrict__ ws)
{
    __shared__ float sc[NB][NF][14];
    __shared__ float sgain[2][NF];       // [0]=in gain, [1]=out gain
    __shared__ float sagg[2][NWAVE][6];  // wave aggregates (double-buffered)
    __shared__ float sS0[2][2];          // block incoming state (double-buffered)

    const int t       = threadIdx.x;
    const int bt      = blockIdx.x >> 2;   // batch
    const int quarter = blockIdx.x & 3;    // which quarter of the signal
    const int lane    = t & 63;
    const int wave    = t >> 6;
    const int frame   = quarter * 6 + (wave >> 1);  // 128 chunks (2 waves)/frame

    // ---------------- coefficient init (threads 0..383) ----------------
    if (t < NB * NF) {
        const int f  = t / NF;
        const int fr = t % NF;
        const float* P = params + (size_t)bt * 50 * NF;
        const float fn = P[(3 * f + 0) * NF + fr];
        const float gn = P[(3 * f + 1) * NF + fr];
        const float qn = P[(3 * f + 2) * NF + fr];

        float Q = __expf(-0.69314718f + qn * 3.4657359f);
        Q = clampf(Q, 0.1f, 100.0f);

        float lo, hi;
        int type;                        // 0 hp, 1 lp, 2 peak, 3 lowshelf, 4 highshelf
        if      (f == 0)  { lo = 20.0f;   hi = 500.0f;   type = 0; }
        else if (f == 15) { lo = 5000.0f; hi = 20000.0f; type = 1; }
        else if (f == 1)  { lo = 50.0f;   hi = 16000.0f; type = 3; }
        else if (f == 14) { lo = 50.0f;   hi = 16000.0f; type = 4; }
        else              { lo = 100.0f;  hi = 15000.0f; type = 2; }

        const float fc = __expf(__logf(lo) + fn * (__logf(hi) - __logf(lo)));
        float g_ = __tanf((float)M_PI * fc / 96000.0f);   // angle <= 0.655 rad, safe
        g_ = clampf(g_, 1e-6f, 100.0f);
        const float gdb = -24.0f + 48.0f * gn;

        float a1, a2, a3, m0, m1, m2;
        if (type == 0 || type == 1) {
            const float k = 1.0f / Q;
            a1 = 1.0f / (1.0f + g_ * (g_ + k)); a2 = g_ * a1; a3 = g_ * a2;
            if (type == 0) { m0 = 1.0f; m1 = -k;   m2 = -1.0f; }
            else           { m0 = 0.0f; m1 = 0.0f; m2 = 1.0f;  }
        } else if (type == 2) {
            const float A = __expf(gdb * (2.30258509f / 40.0f));
            const float k = (gdb >= 0.0f) ? 1.0f / (Q * A) : A / Q;
            a1 = 1.0f / (1.0f + g_ * (g_ + k)); a2 = g_ * a1; a3 = g_ * a2;
            m0 = 1.0f; m1 = k * (A * A - 1.0f); m2 = 0.0f;
        } else {
            const float A  = __expf(gdb * (2.30258509f / 40.0f));
            const float sA = sqrtf(A);
            const float k  = 1.0f / Q;
            float gs;
            if (type == 3) gs = (gdb >= 0.0f) ? g_ / sA : g_ * sA;
            else           gs = (gdb >= 0.0f) ? g_ * sA : g_ / sA;
            a1 = 1.0f / (1.0f + gs * (gs + k)); a2 = gs * a1; a3 = gs * a2;
            if (type == 3) { m0 = 1.0f;  m1 = k * (A - 1.0f);      m2 = A * A - 1.0f; }
            else           { m0 = A * A; m1 = k * (1.0f - A) * A;  m2 = 1.0f - A * A; }
        }

        // affine per-sample form: s' = T s + b*x ; y = c0*ic1 + c1*ic2 + c2*x
        const float q2  = a2 * a2 + a3;
        const float t00 = 2.0f * a1 - 1.0f;
        const float t01 = -2.0f * a2;
        const float t10 = 2.0f * a1 * a2;
        const float t11 = 1.0f - 2.0f * q2;
        const float b0  = 2.0f * a2;
        const float b1  = 2.0f * q2;
        const float c0  = a1 * (m1 + m2 * a2);
        const float c1  = m2 * (1.0f - q2) - m1 * a2;
        const float c2  = m0 + m1 * a2 + m2 * q2;

        // M = T^16 by 4 squarings
        float u00 = t00, u01 = t01, u10 = t10, u11 = t11;
        #pragma unroll
        for (int i = 0; i < 4; i++) {
            const float n00 = u00 * u00 + u01 * u10;
            const float n01 = u00 * u01 + u01 * u11;
            const float n10 = u10 * u00 + u11 * u10;
            const float n11 = u10 * u01 + u11 * u11;
            u00 = n00; u01 = n01; u10 = n10; u11 = n11;
        }

        sc[f][fr][0] = t00; sc[f][fr][1] = t01; sc[f][fr][2] = t10; sc[f][fr][3] = t11;
        sc[f][fr][4] = b0;  sc[f][fr][5] = b1;
        sc[f][fr][6] = c0;  sc[f][fr][7] = c1;  sc[f][fr][8] = c2;
        sc[f][fr][9] = u00; sc[f][fr][10] = u01; sc[f][fr][11] = u10; sc[f][fr][12] = u11;
    }
    if (t >= 384 && t < 384 + 2 * NF) {
        const int idx = t - 384;
        const int which = idx / NF;     // 0 = in gain (row 48), 1 = out gain (row 49)
        const int fr    = idx % NF;
        const float* P = params + (size_t)bt * 50 * NF;
        const float p  = P[(48 + which) * NF + fr];
        const float db = -60.0f + 60.0f * p;
        sgain[which][fr] = __expf(db * (2.30258509f / 20.0f));
    }
    __syncthreads();

    // ---------------- load chunk (with input gain) ----------------
    FOREACH_S(DECL_S)
    {
        const float ing = sgain[0][frame];
        const float* base = audio + (size_t)bt * S
                          + (size_t)(quarter * NCH + t) * CHUNK;
        float4 q;
        q = *(const float4*)(base +  0); s00 = q.x*ing; s01 = q.y*ing; s02 = q.z*ing; s03 = q.w*ing;
        q = *(const float4*)(base +  4); s04 = q.x*ing; s05 = q.y*ing; s06 = q.z*ing; s07 = q.w*ing;
        q = *(const float4*)(base +  8); s08 = q.x*ing; s09 = q.y*ing; s10 = q.z*ing; s11 = q.w*ing;
        q = *(const float4*)(base + 12); s12 = q.x*ing; s13 = q.y*ing; s14 = q.z*ing; s15 = q.w*ing;
    }

    // ---------------- 16 cascaded stages ----------------
    #pragma unroll 1
    for (int f = 0; f < NB; f++) {
        const int buf = f & 1;
        const float t00 = sc[f][frame][0];
        const float t01 = sc[f][frame][1];
        const float t10 = sc[f][frame][2];
        const float t11 = sc[f][frame][3];
        const float b0  = sc[f][frame][4];
        const float b1  = sc[f][frame][5];
        const float c0  = sc[f][frame][6];
        const float c1  = sc[f][frame][7];
        const float c2  = sc[f][frame][8];

        // Phase A: zero-state run over own chunk -> affine constant
        float ic1 = 0.0f, ic2 = 0.0f;
        FOREACH_S(STEPA)

        // own affine map (A = T^16 from LDS, Ac = phase-A constant);
        // 64-lane inclusive scan via shfl_up (lane L = chunks 0..L composed)
        float A00 = sc[f][frame][9];
        float A01 = sc[f][frame][10];
        float A10 = sc[f][frame][11];
        float A11 = sc[f][frame][12];
        float Ac0 = ic1, Ac1 = ic2;
        #pragma unroll
        for (int d = 1; d < 64; d <<= 1) {
            const float l00 = __shfl_up(A00, d);
            const float l01 = __shfl_up(A01, d);
            const float l10 = __shfl_up(A10, d);
            const float l11 = __shfl_up(A11, d);
            const float lc0 = __shfl_up(Ac0, d);
            const float lc1 = __shfl_up(Ac1, d);
            if (lane >= d) {
                const float n00 = A00 * l00 + A01 * l10;
                const float n01 = A00 * l01 + A01 * l11;
                const float n10 = A10 * l00 + A11 * l10;
                const float n11 = A10 * l01 + A11 * l11;
                const float nc0 = A00 * lc0 + A01 * lc1 + Ac0;
                const float nc1 = A10 * lc0 + A11 * lc1 + Ac1;
                A00 = n00; A01 = n01; A10 = n10; A11 = n11;
                Ac0 = nc0; Ac1 = nc1;
            }
        }

        if (lane == 63) {
            sagg[buf][wave][0] = A00; sagg[buf][wave][1] = A01;
            sagg[buf][wave][2] = A10; sagg[buf][wave][3] = A11;
            sagg[buf][wave][4] = Ac0; sagg[buf][wave][5] = Ac1;
        }
        __syncthreads();

        // Second-level scan: every wave redundantly scans the 12 wave
        // aggregates in lanes 0..11 (4 shfl steps) -- replaces R6's serial
        // 11-iteration LDS prefix loop on the critical path.
        float G00 = 1.0f, G01 = 0.0f, G10 = 0.0f, G11 = 1.0f, Gc0 = 0.0f, Gc1 = 0.0f;
        if (lane < NWAVE) {
            G00 = sagg[buf][lane][0]; G01 = sagg[buf][lane][1];
            G10 = sagg[buf][lane][2]; G11 = sagg[buf][lane][3];
            Gc0 = sagg[buf][lane][4]; Gc1 = sagg[buf][lane][5];
        }
        #pragma unroll
        for (int d = 1; d < 16; d <<= 1) {
            const float l00 = __shfl_up(G00, d);
            const float l01 = __shfl_up(G01, d);
            const float l10 = __shfl_up(G10, d);
            const float l11 = __shfl_up(G11, d);
            const float lc0 = __shfl_up(Gc0, d);
            const float lc1 = __shfl_up(Gc1, d);
            if (lane >= d && lane < NWAVE) {
                const float n00 = G00 * l00 + G01 * l10;
                const float n01 = G00 * l01 + G01 * l11;
                const float n10 = G10 * l00 + G11 * l10;
                const float n11 = G10 * l01 + G11 * l11;
                const float nc0 = G00 * lc0 + G01 * lc1 + Gc0;
                const float nc1 = G10 * lc0 + G11 * lc1 + Gc1;
                G00 = n00; G01 = n01; G10 = n10; G11 = n11;
                Gc0 = nc0; Gc1 = nc1;
            }
        }

        const unsigned int tag = (unsigned int)(f + 1);
        unsigned int* stagebase = ws + ((bt * NB + f) * NBLK) * 8;

        // publish own block aggregate (= inclusive scan at lane 11);
        // last block's aggregate is never read -> skip
        if (quarter < NBLK - 1 && wave == 0 && lane == NWAVE - 1) {
            unsigned int* slot = stagebase + quarter * 8;
            float* dp = (float*)(slot + 1);
            __hip_atomic_store(&dp[0], G00, __ATOMIC_RELAXED, __HIP_MEMORY_SCOPE_AGENT);
            __hip_atomic_store(&dp[1], G01, __ATOMIC_RELAXED, __HIP_MEMORY_SCOPE_AGENT);
            __hip_atomic_store(&dp[2], G10, __ATOMIC_RELAXED, __HIP_MEMORY_SCOPE_AGENT);
            __hip_atomic_store(&dp[3], G11, __ATOMIC_RELAXED, __HIP_MEMORY_SCOPE_AGENT);
            __hip_atomic_store(&dp[4], Gc0, __ATOMIC_RELAXED, __HIP_MEMORY_SCOPE_AGENT);
            __hip_atomic_store(&dp[5], Gc1, __ATOMIC_RELAXED, __HIP_MEMORY_SCOPE_AGENT);
            __hip_atomic_store(slot, tag, __ATOMIC_RELEASE, __HIP_MEMORY_SCOPE_AGENT);
        }

        // block incoming state S0 = fold of predecessor aggregates (in order)
        float S0x = 0.0f, S0y = 0.0f;
        if (quarter > 0) {        // block-uniform branch: barrier is legal
            if (t == 0) {
                float sx = 0.0f, sy = 0.0f;
                for (int k2 = 0; k2 < quarter; k2++) {
                    unsigned int* slot = stagebase + k2 * 8;
                    while (__hip_atomic_load(slot, __ATOMIC_ACQUIRE, __HIP_MEMORY_SCOPE_AGENT) != tag) {
                        __builtin_amdgcn_s_sleep(2);
                    }
                    float* dp = (float*)(slot + 1);
                    const float m00 = __hip_atomic_load(&dp[0], __ATOMIC_RELAXED, __HIP_MEMORY_SCOPE_AGENT);
                    const float m01 = __hip_atomic_load(&dp[1], __ATOMIC_RELAXED, __HIP_MEMORY_SCOPE_AGENT);
                    const float m10 = __hip_atomic_load(&dp[2], __ATOMIC_RELAXED, __HIP_MEMORY_SCOPE_AGENT);
                    const float m11 = __hip_atomic_load(&dp[3], __ATOMIC_RELAXED, __HIP_MEMORY_SCOPE_AGENT);
                    const float cc0 = __hip_atomic_load(&dp[4], __ATOMIC_RELAXED, __HIP_MEMORY_SCOPE_AGENT);
                    const float cc1 = __hip_atomic_load(&dp[5], __ATOMIC_RELAXED, __HIP_MEMORY_SCOPE_AGENT);
                    const float nx = m00 * sx + m01 * sy + cc0;
                    const float ny = m10 * sx + m11 * sy + cc1;
                    sx = nx; sy = ny;
                }
                sS0[buf][0] = sx; sS0[buf][1] = sy;
            }
            __syncthreads();
            S0x = sS0[buf][0];
            S0y = sS0[buf][1];
        }

        // wave-exclusive prefix W from second-level scan at lane (wave-1)
        const int wsrc = (wave > 0) ? (wave - 1) : 0;
        float Wm00 = __shfl(G00, wsrc);
        float Wm01 = __shfl(G01, wsrc);
        float Wm10 = __shfl(G10, wsrc);
        float Wm11 = __shfl(G11, wsrc);
        float Wc0  = __shfl(Gc0, wsrc);
        float Wc1  = __shfl(Gc1, wsrc);
        if (wave == 0) { Wm00 = 1.0f; Wm01 = 0.0f; Wm10 = 0.0f; Wm11 = 1.0f; Wc0 = 0.0f; Wc1 = 0.0f; }

        // v = W applied to S0 (incoming state of this wave)
        const float vx = Wm00 * S0x + Wm01 * S0y + Wc0;
        const float vy = Wm10 * S0x + Wm11 * S0y + Wc1;

        // lane-exclusive prefix P, then incoming thread state = P(v)
        float P00 = __shfl_up(A00, 1);
        float P01 = __shfl_up(A01, 1);
        float P10 = __shfl_up(A10, 1);
        float P11 = __shfl_up(A11, 1);
        float Pc0 = __shfl_up(Ac0, 1);
        float Pc1 = __shfl_up(Ac1, 1);
        if (lane == 0) { P00 = 1.0f; P01 = 0.0f; P10 = 0.0f; P11 = 1.0f; Pc0 = 0.0f; Pc1 = 0.0f; }
        ic1 = P00 * vx + P01 * vy + Pc0;
        ic2 = P10 * vx + P11 * vy + Pc1;

        // Phase C: true run from incoming state, write outputs in place
        FOREACH_S(STEPC)
    }

    // ---------------- store (with output gain) ----------------
    {
        const float og = sgain[1][frame];
        float* base = out + (size_t)bt * S + (size_t)(quarter * NCH + t) * CHUNK;
        float4 q;
        q.x = s00*og; q.y = s01*og; q.z = s02*og; q.w = s03*og; *(float4*)(base +  0) = q;
        q.x = s04*og; q.y = s05*og; q.z = s06*og; q.w = s07*og; *(float4*)(base +  4) = q;
        q.x = s08*og; q.y = s09*og; q.z = s10*og; q.w = s11*og; *(float4*)(base +  8) = q;
        q.x = s12*og; q.y = s13*og; q.z = s14*og; q.w = s15*og; *(float4*)(base + 12) = q;
    }
}

extern "C" void kernel_launch(void* const* d_in, const int* in_sizes, int n_in,
                              void* d_out, int out_size, void* d_ws, size_t ws_size,
                              hipStream_t stream)
{
    const float* audio  = (const float*)d_in[0];
    const float* params = (const float*)d_in[1];
    float* out = (float*)d_out;
    unsigned int* ws = (unsigned int*)d_ws;
    biquad_chain_kernel<<<NBLK * NBATCH, NCH, 0, stream>>>(audio, params, out, ws);
}

// Round 8
// 133.470 us; speedup vs baseline: 3.0082x; 1.0282x over previous
//
#include <hip/hip_runtime.h>
#include <math.h>

#define NBATCH 32
#define S      49152
#define NF     24          // frames (2048 samples each)
#define NB     16          // biquads
#define NBLK   4           // blocks per batch
#define CHUNK  16          // samples per thread
#define NCH    768         // threads per block
#define NWAVE  12          // waves per block
// 4 blocks per batch; block covers 768*16 = 12288 samples = 6 frames.

__device__ __forceinline__ float clampf(float x, float lo, float hi) {
    return fminf(fmaxf(x, lo), hi);
}

// 16 named scalar signal registers -- guaranteed SSA (no alloca; R1-R4 showed
// the allocator pins VGPR at 84 and spills float arrays regardless of hints).
#define FOREACH_S(OP) \
    OP(s00) OP(s01) OP(s02) OP(s03) OP(s04) OP(s05) OP(s06) OP(s07) \
    OP(s08) OP(s09) OP(s10) OP(s11) OP(s12) OP(s13) OP(s14) OP(s15)

#define DECL_S(x) float x;

// Phase A step: state only.  s' = T s + b*x
#define STEPA(x) { \
    const float n1_ = fmaf(t00, ic1, fmaf(t01, ic2, b0 * (x))); \
    const float n2_ = fmaf(t10, ic1, fmaf(t11, ic2, b1 * (x))); \
    ic1 = n1_; ic2 = n2_; }

// Phase C step: output + state.  y = c0*ic1 + c1*ic2 + c2*x, in place.
#define STEPC(x) { \
    const float y_  = fmaf(c0, ic1, fmaf(c1, ic2, c2 * (x))); \
    const float n1_ = fmaf(t00, ic1, fmaf(t01, ic2, b0 * (x))); \
    const float n2_ = fmaf(t10, ic1, fmaf(t11, ic2, b1 * (x))); \
    (x) = y_; ic1 = n1_; ic2 = n2_; }

// Cross-block protocol (R6/R7-proven): per (batch,stage,block) write-once
// slot {flag, M00,M01,M10,M11, c0,c1, pad} u32[8]. Block j publishes its OWN
// aggregate affine map (independent of incoming state -> no producer chain)
// and spins on blocks 0..j-1. tag=f+1 never equals the 0xAAAAAAAA ws poison.
//
// R7 post-mortem: 86.8us == R6's 86.5us despite halved per-thread compute ->
// per-stage handshake latency dominates (5.4us/stage). With naive blockIdx
// mapping the 4 quarters of a batch land on 4 DIFFERENT XCDs (round-robin
// dispatch), so every poll is a cross-XCD round trip. R8: swizzle so all
// quarters of a batch share one XCD (blockIdx % 8 == XCD heuristic) -> the
// handshake becomes L2-local. Speed heuristic only; correctness unaffected.
__global__ __launch_bounds__(NCH, 3)
void biquad_chain_kernel(const float* __restrict__ audio,
                         const float* __restrict__ params,
                         float* __restrict__ out,
                         unsigned int* __restrict__ ws)
{
    __shared__ float sc[NB][NF][14];
    __shared__ float sgain[2][NF];       // [0]=in gain, [1]=out gain
    __shared__ float sagg[2][NWAVE][6];  // wave aggregates (double-buffered)
    __shared__ float sS0[2][2];          // block incoming state (double-buffered)

    const int t       = threadIdx.x;
    // XCD co-location swizzle: 128 blocks, XCD = blockIdx % 8 (round-robin
    // heuristic). xcd owns batches [4*xcd, 4*xcd+4); the 4 quarters of a
    // batch are at blockIdx ≡ xcd (mod 8) -> same XCD, shared L2.
    const int xcd     = blockIdx.x & 7;
    const int slot_   = blockIdx.x >> 3;   // 16 slots per XCD
    const int bt      = xcd * 4 + (slot_ & 3);   // batch
    const int quarter = slot_ >> 2;              // which quarter of the signal
    const int lane    = t & 63;
    const int wave    = t >> 6;
    const int frame   = quarter * 6 + (wave >> 1);  // 128 chunks (2 waves)/frame

    // ---------------- coefficient init (threads 0..383) ----------------
    if (t < NB * NF) {
        const int f  = t / NF;
        const int fr = t % NF;
        const float* P = params + (size_t)bt * 50 * NF;
        const float fn = P[(3 * f + 0) * NF + fr];
        const float gn = P[(3 * f + 1) * NF + fr];
        const float qn = P[(3 * f + 2) * NF + fr];

        float Q = __expf(-0.69314718f + qn * 3.4657359f);
        Q = clampf(Q, 0.1f, 100.0f);

        float lo, hi;
        int type;                        // 0 hp, 1 lp, 2 peak, 3 lowshelf, 4 highshelf
        if      (f == 0)  { lo = 20.0f;   hi = 500.0f;   type = 0; }
        else if (f == 15) { lo = 5000.0f; hi = 20000.0f; type = 1; }
        else if (f == 1)  { lo = 50.0f;   hi = 16000.0f; type = 3; }
        else if (f == 14) { lo = 50.0f;   hi = 16000.0f; type = 4; }
        else              { lo = 100.0f;  hi = 15000.0f; type = 2; }

        const float fc = __expf(__logf(lo) + fn * (__logf(hi) - __logf(lo)));
        float g_ = __tanf((float)M_PI * fc / 96000.0f);   // angle <= 0.655 rad, safe
        g_ = clampf(g_, 1e-6f, 100.0f);
        const float gdb = -24.0f + 48.0f * gn;

        float a1, a2, a3, m0, m1, m2;
        if (type == 0 || type == 1) {
            const float k = 1.0f / Q;
            a1 = 1.0f / (1.0f + g_ * (g_ + k)); a2 = g_ * a1; a3 = g_ * a2;
            if (type == 0) { m0 = 1.0f; m1 = -k;   m2 = -1.0f; }
            else           { m0 = 0.0f; m1 = 0.0f; m2 = 1.0f;  }
        } else if (type == 2) {
            const float A = __expf(gdb * (2.30258509f / 40.0f));
            const float k = (gdb >= 0.0f) ? 1.0f / (Q * A) : A / Q;
            a1 = 1.0f / (1.0f + g_ * (g_ + k)); a2 = g_ * a1; a3 = g_ * a2;
            m0 = 1.0f; m1 = k * (A * A - 1.0f); m2 = 0.0f;
        } else {
            const float A  = __expf(gdb * (2.30258509f / 40.0f));
            const float sA = sqrtf(A);
            const float k  = 1.0f / Q;
            float gs;
            if (type == 3) gs = (gdb >= 0.0f) ? g_ / sA : g_ * sA;
            else           gs = (gdb >= 0.0f) ? g_ * sA : g_ / sA;
            a1 = 1.0f / (1.0f + gs * (gs + k)); a2 = gs * a1; a3 = gs * a2;
            if (type == 3) { m0 = 1.0f;  m1 = k * (A - 1.0f);      m2 = A * A - 1.0f; }
            else           { m0 = A * A; m1 = k * (1.0f - A) * A;  m2 = 1.0f - A * A; }
        }

        // affine per-sample form: s' = T s + b*x ; y = c0*ic1 + c1*ic2 + c2*x
        const float q2  = a2 * a2 + a3;
        const float t00 = 2.0f * a1 - 1.0f;
        const float t01 = -2.0f * a2;
        const float t10 = 2.0f * a1 * a2;
        const float t11 = 1.0f - 2.0f * q2;
        const float b0  = 2.0f * a2;
        const float b1  = 2.0f * q2;
        const float c0  = a1 * (m1 + m2 * a2);
        const float c1  = m2 * (1.0f - q2) - m1 * a2;
        const float c2  = m0 + m1 * a2 + m2 * q2;

        // M = T^16 by 4 squarings
        float u00 = t00, u01 = t01, u10 = t10, u11 = t11;
        #pragma unroll
        for (int i = 0; i < 4; i++) {
            const float n00 = u00 * u00 + u01 * u10;
            const float n01 = u00 * u01 + u01 * u11;
            const float n10 = u10 * u00 + u11 * u10;
            const float n11 = u10 * u01 + u11 * u11;
            u00 = n00; u01 = n01; u10 = n10; u11 = n11;
        }

        sc[f][fr][0] = t00; sc[f][fr][1] = t01; sc[f][fr][2] = t10; sc[f][fr][3] = t11;
        sc[f][fr][4] = b0;  sc[f][fr][5] = b1;
        sc[f][fr][6] = c0;  sc[f][fr][7] = c1;  sc[f][fr][8] = c2;
        sc[f][fr][9] = u00; sc[f][fr][10] = u01; sc[f][fr][11] = u10; sc[f][fr][12] = u11;
    }
    if (t >= 384 && t < 384 + 2 * NF) {
        const int idx = t - 384;
        const int which = idx / NF;     // 0 = in gain (row 48), 1 = out gain (row 49)
        const int fr    = idx % NF;
        const float* P = params + (size_t)bt * 50 * NF;
        const float p  = P[(48 + which) * NF + fr];
        const float db = -60.0f + 60.0f * p;
        sgain[which][fr] = __expf(db * (2.30258509f / 20.0f));
    }
    __syncthreads();

    // ---------------- load chunk (with input gain) ----------------
    FOREACH_S(DECL_S)
    {
        const float ing = sgain[0][frame];
        const float* base = audio + (size_t)bt * S
                          + (size_t)(quarter * NCH + t) * CHUNK;
        float4 q;
        q = *(const float4*)(base +  0); s00 = q.x*ing; s01 = q.y*ing; s02 = q.z*ing; s03 = q.w*ing;
        q = *(const float4*)(base +  4); s04 = q.x*ing; s05 = q.y*ing; s06 = q.z*ing; s07 = q.w*ing;
        q = *(const float4*)(base +  8); s08 = q.x*ing; s09 = q.y*ing; s10 = q.z*ing; s11 = q.w*ing;
        q = *(const float4*)(base + 12); s12 = q.x*ing; s13 = q.y*ing; s14 = q.z*ing; s15 = q.w*ing;
    }

    // ---------------- 16 cascaded stages ----------------
    #pragma unroll 1
    for (int f = 0; f < NB; f++) {
        const int buf = f & 1;
        const float t00 = sc[f][frame][0];
        const float t01 = sc[f][frame][1];
        const float t10 = sc[f][frame][2];
        const float t11 = sc[f][frame][3];
        const float b0  = sc[f][frame][4];
        const float b1  = sc[f][frame][5];
        const float c0  = sc[f][frame][6];
        const float c1  = sc[f][frame][7];
        const float c2  = sc[f][frame][8];

        // Phase A: zero-state run over own chunk -> affine constant
        float ic1 = 0.0f, ic2 = 0.0f;
        FOREACH_S(STEPA)

        // own affine map (A = T^16 from LDS, Ac = phase-A constant);
        // 64-lane inclusive scan via shfl_up (lane L = chunks 0..L composed)
        float A00 = sc[f][frame][9];
        float A01 = sc[f][frame][10];
        float A10 = sc[f][frame][11];
        float A11 = sc[f][frame][12];
        float Ac0 = ic1, Ac1 = ic2;
        #pragma unroll
        for (int d = 1; d < 64; d <<= 1) {
            const float l00 = __shfl_up(A00, d);
            const float l01 = __shfl_up(A01, d);
            const float l10 = __shfl_up(A10, d);
            const float l11 = __shfl_up(A11, d);
            const float lc0 = __shfl_up(Ac0, d);
            const float lc1 = __shfl_up(Ac1, d);
            if (lane >= d) {
                const float n00 = A00 * l00 + A01 * l10;
                const float n01 = A00 * l01 + A01 * l11;
                const float n10 = A10 * l00 + A11 * l10;
                const float n11 = A10 * l01 + A11 * l11;
                const float nc0 = A00 * lc0 + A01 * lc1 + Ac0;
                const float nc1 = A10 * lc0 + A11 * lc1 + Ac1;
                A00 = n00; A01 = n01; A10 = n10; A11 = n11;
                Ac0 = nc0; Ac1 = nc1;
            }
        }

        if (lane == 63) {
            sagg[buf][wave][0] = A00; sagg[buf][wave][1] = A01;
            sagg[buf][wave][2] = A10; sagg[buf][wave][3] = A11;
            sagg[buf][wave][4] = Ac0; sagg[buf][wave][5] = Ac1;
        }
        __syncthreads();

        // Second-level scan: every wave redundantly scans the 12 wave
        // aggregates in lanes 0..11 (4 shfl steps).
        float G00 = 1.0f, G01 = 0.0f, G10 = 0.0f, G11 = 1.0f, Gc0 = 0.0f, Gc1 = 0.0f;
        if (lane < NWAVE) {
            G00 = sagg[buf][lane][0]; G01 = sagg[buf][lane][1];
            G10 = sagg[buf][lane][2]; G11 = sagg[buf][lane][3];
            Gc0 = sagg[buf][lane][4]; Gc1 = sagg[buf][lane][5];
        }
        #pragma unroll
        for (int d = 1; d < 16; d <<= 1) {
            const float l00 = __shfl_up(G00, d);
            const float l01 = __shfl_up(G01, d);
            const float l10 = __shfl_up(G10, d);
            const float l11 = __shfl_up(G11, d);
            const float lc0 = __shfl_up(Gc0, d);
            const float lc1 = __shfl_up(Gc1, d);
            if (lane >= d && lane < NWAVE) {
                const float n00 = G00 * l00 + G01 * l10;
                const float n01 = G00 * l01 + G01 * l11;
                const float n10 = G10 * l00 + G11 * l10;
                const float n11 = G10 * l01 + G11 * l11;
                const float nc0 = G00 * lc0 + G01 * lc1 + Gc0;
                const float nc1 = G10 * lc0 + G11 * lc1 + Gc1;
                G00 = n00; G01 = n01; G10 = n10; G11 = n11;
                Gc0 = nc0; Gc1 = nc1;
            }
        }

        const unsigned int tag = (unsigned int)(f + 1);
        unsigned int* stagebase = ws + ((bt * NB + f) * NBLK) * 8;

        // publish own block aggregate (= inclusive scan at lane 11);
        // last block's aggregate is never read -> skip
        if (quarter < NBLK - 1 && wave == 0 && lane == NWAVE - 1) {
            unsigned int* slot = stagebase + quarter * 8;
            float* dp = (float*)(slot + 1);
            __hip_atomic_store(&dp[0], G00, __ATOMIC_RELAXED, __HIP_MEMORY_SCOPE_AGENT);
            __hip_atomic_store(&dp[1], G01, __ATOMIC_RELAXED, __HIP_MEMORY_SCOPE_AGENT);
            __hip_atomic_store(&dp[2], G10, __ATOMIC_RELAXED, __HIP_MEMORY_SCOPE_AGENT);
            __hip_atomic_store(&dp[3], G11, __ATOMIC_RELAXED, __HIP_MEMORY_SCOPE_AGENT);
            __hip_atomic_store(&dp[4], Gc0, __ATOMIC_RELAXED, __HIP_MEMORY_SCOPE_AGENT);
            __hip_atomic_store(&dp[5], Gc1, __ATOMIC_RELAXED, __HIP_MEMORY_SCOPE_AGENT);
            __hip_atomic_store(slot, tag, __ATOMIC_RELEASE, __HIP_MEMORY_SCOPE_AGENT);
        }

        // block incoming state S0 = fold of predecessor aggregates (in order)
        float S0x = 0.0f, S0y = 0.0f;
        if (quarter > 0) {        // block-uniform branch: barrier is legal
            if (t == 0) {
                float sx = 0.0f, sy = 0.0f;
                for (int k2 = 0; k2 < quarter; k2++) {
                    unsigned int* slot = stagebase + k2 * 8;
                    while (__hip_atomic_load(slot, __ATOMIC_ACQUIRE, __HIP_MEMORY_SCOPE_AGENT) != tag) {
                        __builtin_amdgcn_s_sleep(1);
                    }
                    float* dp = (float*)(slot + 1);
                    const float m00 = __hip_atomic_load(&dp[0], __ATOMIC_RELAXED, __HIP_MEMORY_SCOPE_AGENT);
                    const float m01 = __hip_atomic_load(&dp[1], __ATOMIC_RELAXED, __HIP_MEMORY_SCOPE_AGENT);
                    const float m10 = __hip_atomic_load(&dp[2], __ATOMIC_RELAXED, __HIP_MEMORY_SCOPE_AGENT);
                    const float m11 = __hip_atomic_load(&dp[3], __ATOMIC_RELAXED, __HIP_MEMORY_SCOPE_AGENT);
                    const float cc0 = __hip_atomic_load(&dp[4], __ATOMIC_RELAXED, __HIP_MEMORY_SCOPE_AGENT);
                    const float cc1 = __hip_atomic_load(&dp[5], __ATOMIC_RELAXED, __HIP_MEMORY_SCOPE_AGENT);
                    const float nx = m00 * sx + m01 * sy + cc0;
                    const float ny = m10 * sx + m11 * sy + cc1;
                    sx = nx; sy = ny;
                }
                sS0[buf][0] = sx; sS0[buf][1] = sy;
            }
            __syncthreads();
            S0x = sS0[buf][0];
            S0y = sS0[buf][1];
        }

        // wave-exclusive prefix W from second-level scan at lane (wave-1)
        const int wsrc = (wave > 0) ? (wave - 1) : 0;
        float Wm00 = __shfl(G00, wsrc);
        float Wm01 = __shfl(G01, wsrc);
        float Wm10 = __shfl(G10, wsrc);
        float Wm11 = __shfl(G11, wsrc);
        float Wc0  = __shfl(Gc0, wsrc);
        float Wc1  = __shfl(Gc1, wsrc);
        if (wave == 0) { Wm00 = 1.0f; Wm01 = 0.0f; Wm10 = 0.0f; Wm11 = 1.0f; Wc0 = 0.0f; Wc1 = 0.0f; }

        // v = W applied to S0 (incoming state of this wave)
        const float vx = Wm00 * S0x + Wm01 * S0y + Wc0;
        const float vy = Wm10 * S0x + Wm11 * S0y + Wc1;

        // lane-exclusive prefix P, then incoming thread state = P(v)
        float P00 = __shfl_up(A00, 1);
        float P01 = __shfl_up(A01, 1);
        float P10 = __shfl_up(A10, 1);
        float P11 = __shfl_up(A11, 1);
        float Pc0 = __shfl_up(Ac0, 1);
        float Pc1 = __shfl_up(Ac1, 1);
        if (lane == 0) { P00 = 1.0f; P01 = 0.0f; P10 = 0.0f; P11 = 1.0f; Pc0 = 0.0f; Pc1 = 0.0f; }
        ic1 = P00 * vx + P01 * vy + Pc0;
        ic2 = P10 * vx + P11 * vy + Pc1;

        // Phase C: true run from incoming state, write outputs in place
        FOREACH_S(STEPC)
    }

    // ---------------- store (with output gain) ----------------
    {
        const float og = sgain[1][frame];
        float* base = out + (size_t)bt * S + (size_t)(quarter * NCH + t) * CHUNK;
        float4 q;
        q.x = s00*og; q.y = s01*og; q.z = s02*og; q.w = s03*og; *(float4*)(base +  0) = q;
        q.x = s04*og; q.y = s05*og; q.z = s06*og; q.w = s07*og; *(float4*)(base +  4) = q;
        q.x = s08*og; q.y = s09*og; q.z = s10*og; q.w = s11*og; *(float4*)(base +  8) = q;
        q.x = s12*og; q.y = s13*og; q.z = s14*og; q.w = s15*og; *(float4*)(base + 12) = q;
    }
}

extern "C" void kernel_launch(void* const* d_in, const int* in_sizes, int n_in,
                              void* d_out, int out_size, void* d_ws, size_t ws_size,
                              hipStream_t stream)
{
    const float* audio  = (const float*)d_in[0];
    const float* params = (const float*)d_in[1];
    float* out = (float*)d_out;
    unsigned int* ws = (unsigned int*)d_ws;
    biquad_chain_kernel<<<NBLK * NBATCH, NCH, 0, stream>>>(audio, params, out, ws);
}

// Round 9
// 124.828 us; speedup vs baseline: 3.2164x; 1.0692x over previous
//
#include <hip/hip_runtime.h>
#include <math.h>

#define NBATCH 32
#define S      49152
#define NF     24          // frames (2048 samples each)
#define NB     16          // biquads
#define NBLK   4           // blocks per batch
#define CHUNK  16          // samples per thread
#define NCH    768         // threads per block
#define NWAVE  12          // waves per block
// 4 blocks per batch; block covers 768*16 = 12288 samples = 6 frames.

__device__ __forceinline__ float clampf(float x, float lo, float hi) {
    return fminf(fmaxf(x, lo), hi);
}

// 16 named scalar signal registers -- guaranteed SSA (no alloca; R1-R4 showed
// the allocator pins VGPR at 84 and spills float arrays regardless of hints).
#define FOREACH_S(OP) \
    OP(s00) OP(s01) OP(s02) OP(s03) OP(s04) OP(s05) OP(s06) OP(s07) \
    OP(s08) OP(s09) OP(s10) OP(s11) OP(s12) OP(s13) OP(s14) OP(s15)

#define DECL_S(x) float x;

// Phase A step: state only.  s' = T s + b*x
#define STEPA(x) { \
    const float n1_ = fmaf(t00, ic1, fmaf(t01, ic2, b0 * (x))); \
    const float n2_ = fmaf(t10, ic1, fmaf(t11, ic2, b1 * (x))); \
    ic1 = n1_; ic2 = n2_; }

// Phase C step: output + state.  y = c0*ic1 + c1*ic2 + c2*x, in place.
#define STEPC(x) { \
    const float y_  = fmaf(c0, ic1, fmaf(c1, ic2, c2 * (x))); \
    const float n1_ = fmaf(t00, ic1, fmaf(t01, ic2, b0 * (x))); \
    const float n2_ = fmaf(t10, ic1, fmaf(t11, ic2, b1 * (x))); \
    (x) = y_; ic1 = n1_; ic2 = n2_; }

// R8 post-mortem: DS-pipe saturation is the bottleneck (~91 wave-DS-ops/stage
// x12 waves x ~5.8cy ≈ 6.3k cy/stage ≈ the whole 82us). R9 cuts DS ~4x:
//  - all lanes of a wave share frame -> scan matrices are powers of one
//    wave-uniform M=T^16: constants-only Kogge-Stone (2 shfl/step, M^d in
//    registers, squared in place); M^64 aggregate falls out free
//  - lane prefix = M^lane via in-register binary exponentiation (0 DS)
//  - second-level scan on wave 0 only; it writes per-wave incoming state v
//    (2 floats) to LDS; other waves read 2 floats
//  - coefficients read as 4x float4 (stride-16 LDS layout)
// Cross-block protocol unchanged (R6-proven write-once slots, tag=f+1).
__global__ __launch_bounds__(NCH, 3)
void biquad_chain_kernel(const float* __restrict__ audio,
                         const float* __restrict__ params,
                         float* __restrict__ out,
                         unsigned int* __restrict__ ws)
{
    __shared__ float sc[NB][NF][16];     // stride 16 -> float4-aligned reads
    __shared__ float sgain[2][NF];       // [0]=in gain, [1]=out gain
    __shared__ float4 saggM[NWAVE];      // wave aggregate matrices
    __shared__ float  saggC[NWAVE][2];   // wave aggregate constants
    __shared__ float  sv[NWAVE][2];      // per-wave incoming state

    const int t       = threadIdx.x;
    // XCD co-location swizzle (R8, kept): all 4 quarters of a batch land on
    // blockIdx ≡ xcd (mod 8) -> same XCD, L2-local handshake.
    const int xcd     = blockIdx.x & 7;
    const int slot_   = blockIdx.x >> 3;
    const int bt      = xcd * 4 + (slot_ & 3);   // batch
    const int quarter = slot_ >> 2;              // which quarter of the signal
    const int lane    = t & 63;
    const int wave    = t >> 6;
    const int frame   = quarter * 6 + (wave >> 1);  // 2 waves per 2048-frame

    // ---------------- coefficient init (threads 0..383) ----------------
    if (t < NB * NF) {
        const int f  = t / NF;
        const int fr = t % NF;
        const float* P = params + (size_t)bt * 50 * NF;
        const float fn = P[(3 * f + 0) * NF + fr];
        const float gn = P[(3 * f + 1) * NF + fr];
        const float qn = P[(3 * f + 2) * NF + fr];

        float Q = __expf(-0.69314718f + qn * 3.4657359f);
        Q = clampf(Q, 0.1f, 100.0f);

        float lo, hi;
        int type;                        // 0 hp, 1 lp, 2 peak, 3 lowshelf, 4 highshelf
        if      (f == 0)  { lo = 20.0f;   hi = 500.0f;   type = 0; }
        else if (f == 15) { lo = 5000.0f; hi = 20000.0f; type = 1; }
        else if (f == 1)  { lo = 50.0f;   hi = 16000.0f; type = 3; }
        else if (f == 14) { lo = 50.0f;   hi = 16000.0f; type = 4; }
        else              { lo = 100.0f;  hi = 15000.0f; type = 2; }

        const float fc = __expf(__logf(lo) + fn * (__logf(hi) - __logf(lo)));
        float g_ = __tanf((float)M_PI * fc / 96000.0f);   // angle <= 0.655 rad, safe
        g_ = clampf(g_, 1e-6f, 100.0f);
        const float gdb = -24.0f + 48.0f * gn;

        float a1, a2, a3, m0, m1, m2;
        if (type == 0 || type == 1) {
            const float k = 1.0f / Q;
            a1 = 1.0f / (1.0f + g_ * (g_ + k)); a2 = g_ * a1; a3 = g_ * a2;
            if (type == 0) { m0 = 1.0f; m1 = -k;   m2 = -1.0f; }
            else           { m0 = 0.0f; m1 = 0.0f; m2 = 1.0f;  }
        } else if (type == 2) {
            const float A = __expf(gdb * (2.30258509f / 40.0f));
            const float k = (gdb >= 0.0f) ? 1.0f / (Q * A) : A / Q;
            a1 = 1.0f / (1.0f + g_ * (g_ + k)); a2 = g_ * a1; a3 = g_ * a2;
            m0 = 1.0f; m1 = k * (A * A - 1.0f); m2 = 0.0f;
        } else {
            const float A  = __expf(gdb * (2.30258509f / 40.0f));
            const float sA = sqrtf(A);
            const float k  = 1.0f / Q;
            float gs;
            if (type == 3) gs = (gdb >= 0.0f) ? g_ / sA : g_ * sA;
            else           gs = (gdb >= 0.0f) ? g_ * sA : g_ / sA;
            a1 = 1.0f / (1.0f + gs * (gs + k)); a2 = gs * a1; a3 = gs * a2;
            if (type == 3) { m0 = 1.0f;  m1 = k * (A - 1.0f);      m2 = A * A - 1.0f; }
            else           { m0 = A * A; m1 = k * (1.0f - A) * A;  m2 = 1.0f - A * A; }
        }

        // affine per-sample form: s' = T s + b*x ; y = c0*ic1 + c1*ic2 + c2*x
        const float q2  = a2 * a2 + a3;
        const float t00 = 2.0f * a1 - 1.0f;
        const float t01 = -2.0f * a2;
        const float t10 = 2.0f * a1 * a2;
        const float t11 = 1.0f - 2.0f * q2;
        const float b0  = 2.0f * a2;
        const float b1  = 2.0f * q2;
        const float c0  = a1 * (m1 + m2 * a2);
        const float c1  = m2 * (1.0f - q2) - m1 * a2;
        const float c2  = m0 + m1 * a2 + m2 * q2;

        // M = T^16 by 4 squarings
        float u00 = t00, u01 = t01, u10 = t10, u11 = t11;
        #pragma unroll
        for (int i = 0; i < 4; i++) {
            const float n00 = u00 * u00 + u01 * u10;
            const float n01 = u00 * u01 + u01 * u11;
            const float n10 = u10 * u00 + u11 * u10;
            const float n11 = u10 * u01 + u11 * u11;
            u00 = n00; u01 = n01; u10 = n10; u11 = n11;
        }

        // layout for float4 reads:
        // [0-3]=t00,t01,t10,t11  [4-7]=b0,b1,c0,c1  [8-11]=c2,M00,M01,M10  [12]=M11
        sc[f][fr][0] = t00; sc[f][fr][1] = t01; sc[f][fr][2] = t10; sc[f][fr][3] = t11;
        sc[f][fr][4] = b0;  sc[f][fr][5] = b1;  sc[f][fr][6] = c0;  sc[f][fr][7] = c1;
        sc[f][fr][8] = c2;  sc[f][fr][9] = u00; sc[f][fr][10] = u01; sc[f][fr][11] = u10;
        sc[f][fr][12] = u11;
    }
    if (t >= 384 && t < 384 + 2 * NF) {
        const int idx = t - 384;
        const int which = idx / NF;     // 0 = in gain (row 48), 1 = out gain (row 49)
        const int fr    = idx % NF;
        const float* P = params + (size_t)bt * 50 * NF;
        const float p  = P[(48 + which) * NF + fr];
        const float db = -60.0f + 60.0f * p;
        sgain[which][fr] = __expf(db * (2.30258509f / 20.0f));
    }
    __syncthreads();

    // ---------------- load chunk (with input gain) ----------------
    FOREACH_S(DECL_S)
    {
        const float ing = sgain[0][frame];
        const float* base = audio + (size_t)bt * S
                          + (size_t)(quarter * NCH + t) * CHUNK;
        float4 q;
        q = *(const float4*)(base +  0); s00 = q.x*ing; s01 = q.y*ing; s02 = q.z*ing; s03 = q.w*ing;
        q = *(const float4*)(base +  4); s04 = q.x*ing; s05 = q.y*ing; s06 = q.z*ing; s07 = q.w*ing;
        q = *(const float4*)(base +  8); s08 = q.x*ing; s09 = q.y*ing; s10 = q.z*ing; s11 = q.w*ing;
        q = *(const float4*)(base + 12); s12 = q.x*ing; s13 = q.y*ing; s14 = q.z*ing; s15 = q.w*ing;
    }

    // ---------------- 16 cascaded stages ----------------
    #pragma unroll 1
    for (int f = 0; f < NB; f++) {
        const float4 q0 = *(const float4*)&sc[f][frame][0];  // t00 t01 t10 t11
        const float4 q1 = *(const float4*)&sc[f][frame][4];  // b0 b1 c0 c1
        const float4 q2 = *(const float4*)&sc[f][frame][8];  // c2 M00 M01 M10
        const float  M11v = sc[f][frame][12];
        const float t00 = q0.x, t01 = q0.y, t10 = q0.z, t11 = q0.w;
        const float b0  = q1.x, b1  = q1.y, c0  = q1.z, c1  = q1.w;
        const float c2  = q2.x;

        // Phase A: zero-state run over own chunk -> affine constant
        float ic1 = 0.0f, ic2 = 0.0f;
        FOREACH_S(STEPA)

        // constants-only Kogge-Stone: all lanes share M=T^16, so step d
        // composes with wave-uniform M^d (register, squared in place).
        float Md00 = q2.y, Md01 = q2.z, Md10 = q2.w, Md11 = M11v;
        float Ac0 = ic1, Ac1 = ic2;
        #pragma unroll
        for (int d = 1; d < 64; d <<= 1) {
            const float lc0 = __shfl_up(Ac0, d);
            const float lc1 = __shfl_up(Ac1, d);
            if (lane >= d) {
                Ac0 = fmaf(Md00, lc0, fmaf(Md01, lc1, Ac0));
                Ac1 = fmaf(Md10, lc0, fmaf(Md11, lc1, Ac1));
            }
            const float n00 = Md00 * Md00 + Md01 * Md10;
            const float n01 = Md00 * Md01 + Md01 * Md11;
            const float n10 = Md10 * Md00 + Md11 * Md10;
            const float n11 = Md10 * Md01 + Md11 * Md11;
            Md00 = n00; Md01 = n01; Md10 = n10; Md11 = n11;
        }
        // Md = M^64 (wave aggregate matrix); Ac at lane 63 = aggregate const

        if (lane == 63) {
            saggM[wave] = make_float4(Md00, Md01, Md10, Md11);
            saggC[wave][0] = Ac0; saggC[wave][1] = Ac1;
        }
        __syncthreads();

        const unsigned int tag = (unsigned int)(f + 1);
        unsigned int* stagebase = ws + ((bt * NB + f) * NBLK) * 8;

        // Second level on wave 0 only: scan 12 aggregates, publish block
        // aggregate, poll predecessors, distribute per-wave incoming state v.
        if (wave == 0) {
            float G00 = 1.0f, G01 = 0.0f, G10 = 0.0f, G11 = 1.0f, Gc0 = 0.0f, Gc1 = 0.0f;
            if (lane < NWAVE) {
                const float4 m = saggM[lane];
                G00 = m.x; G01 = m.y; G10 = m.z; G11 = m.w;
                Gc0 = saggC[lane][0]; Gc1 = saggC[lane][1];
            }
            #pragma unroll
            for (int d = 1; d < 16; d <<= 1) {
                const float l00 = __shfl_up(G00, d);
                const float l01 = __shfl_up(G01, d);
                const float l10 = __shfl_up(G10, d);
                const float l11 = __shfl_up(G11, d);
                const float lc0 = __shfl_up(Gc0, d);
                const float lc1 = __shfl_up(Gc1, d);
                if (lane >= d && lane < NWAVE) {
                    const float n00 = G00 * l00 + G01 * l10;
                    const float n01 = G00 * l01 + G01 * l11;
                    const float n10 = G10 * l00 + G11 * l10;
                    const float n11 = G10 * l01 + G11 * l11;
                    const float nc0 = G00 * lc0 + G01 * lc1 + Gc0;
                    const float nc1 = G10 * lc0 + G11 * lc1 + Gc1;
                    G00 = n00; G01 = n01; G10 = n10; G11 = n11;
                    Gc0 = nc0; Gc1 = nc1;
                }
            }

            // publish block aggregate (inclusive at lane 11) ASAP
            if (quarter < NBLK - 1 && lane == NWAVE - 1) {
                unsigned int* slot = stagebase + quarter * 8;
                float* dp = (float*)(slot + 1);
                __hip_atomic_store(&dp[0], G00, __ATOMIC_RELAXED, __HIP_MEMORY_SCOPE_AGENT);
                __hip_atomic_store(&dp[1], G01, __ATOMIC_RELAXED, __HIP_MEMORY_SCOPE_AGENT);
                __hip_atomic_store(&dp[2], G10, __ATOMIC_RELAXED, __HIP_MEMORY_SCOPE_AGENT);
                __hip_atomic_store(&dp[3], G11, __ATOMIC_RELAXED, __HIP_MEMORY_SCOPE_AGENT);
                __hip_atomic_store(&dp[4], Gc0, __ATOMIC_RELAXED, __HIP_MEMORY_SCOPE_AGENT);
                __hip_atomic_store(&dp[5], Gc1, __ATOMIC_RELAXED, __HIP_MEMORY_SCOPE_AGENT);
                __hip_atomic_store(slot, tag, __ATOMIC_RELEASE, __HIP_MEMORY_SCOPE_AGENT);
            }

            // exclusive wave prefix
            float P00 = __shfl_up(G00, 1);
            float P01 = __shfl_up(G01, 1);
            float P10 = __shfl_up(G10, 1);
            float P11 = __shfl_up(G11, 1);
            float Pc0 = __shfl_up(Gc0, 1);
            float Pc1 = __shfl_up(Gc1, 1);
            if (lane == 0) { P00 = 1.0f; P01 = 0.0f; P10 = 0.0f; P11 = 1.0f; Pc0 = 0.0f; Pc1 = 0.0f; }

            // lane 0: poll predecessor blocks, fold block incoming state S0
            float S0x = 0.0f, S0y = 0.0f;
            if (lane == 0 && quarter > 0) {
                float sx = 0.0f, sy = 0.0f;
                for (int k2 = 0; k2 < quarter; k2++) {
                    unsigned int* slot = stagebase + k2 * 8;
                    while (__hip_atomic_load(slot, __ATOMIC_ACQUIRE, __HIP_MEMORY_SCOPE_AGENT) != tag) {
                        __builtin_amdgcn_s_sleep(1);
                    }
                    float* dp = (float*)(slot + 1);
                    const float m00 = __hip_atomic_load(&dp[0], __ATOMIC_RELAXED, __HIP_MEMORY_SCOPE_AGENT);
                    const float m01 = __hip_atomic_load(&dp[1], __ATOMIC_RELAXED, __HIP_MEMORY_SCOPE_AGENT);
                    const float m10 = __hip_atomic_load(&dp[2], __ATOMIC_RELAXED, __HIP_MEMORY_SCOPE_AGENT);
                    const float m11 = __hip_atomic_load(&dp[3], __ATOMIC_RELAXED, __HIP_MEMORY_SCOPE_AGENT);
                    const float cc0 = __hip_atomic_load(&dp[4], __ATOMIC_RELAXED, __HIP_MEMORY_SCOPE_AGENT);
                    const float cc1 = __hip_atomic_load(&dp[5], __ATOMIC_RELAXED, __HIP_MEMORY_SCOPE_AGENT);
                    const float nx = m00 * sx + m01 * sy + cc0;
                    const float ny = m10 * sx + m11 * sy + cc1;
                    sx = nx; sy = ny;
                }
                S0x = sx; S0y = sy;
            }
            S0x = __shfl(S0x, 0);
            S0y = __shfl(S0y, 0);

            // per-wave incoming state v = P(S0); lanes 0..11 write to LDS
            if (lane < NWAVE) {
                sv[lane][0] = fmaf(P00, S0x, fmaf(P01, S0y, Pc0));
                sv[lane][1] = fmaf(P10, S0x, fmaf(P11, S0y, Pc1));
            }
        }
        __syncthreads();

        const float vx = sv[wave][0];
        const float vy = sv[wave][1];

        // lane-exclusive constants
        float ce0 = __shfl_up(Ac0, 1);
        float ce1 = __shfl_up(Ac1, 1);
        if (lane == 0) { ce0 = 0.0f; ce1 = 0.0f; }

        // w = M^lane * v via in-register binary exponentiation (powers of the
        // same M commute, order irrelevant). 0 DS ops.
        float w0 = vx, w1 = vy;
        float p00 = q2.y, p01 = q2.z, p10 = q2.w, p11 = M11v;
        #pragma unroll
        for (int b = 0; b < 6; b++) {
            if (lane & (1 << b)) {
                const float nw0 = fmaf(p00, w0, p01 * w1);
                const float nw1 = fmaf(p10, w0, p11 * w1);
                w0 = nw0; w1 = nw1;
            }
            if (b < 5) {
                const float n00 = p00 * p00 + p01 * p10;
                const float n01 = p00 * p01 + p01 * p11;
                const float n10 = p10 * p00 + p11 * p10;
                const float n11 = p10 * p01 + p11 * p11;
                p00 = n00; p01 = n01; p10 = n10; p11 = n11;
            }
        }
        ic1 = w0 + ce0;
        ic2 = w1 + ce1;

        // Phase C: true run from incoming state, write outputs in place
        FOREACH_S(STEPC)
    }

    // ---------------- store (with output gain) ----------------
    {
        const float og = sgain[1][frame];
        float* base = out + (size_t)bt * S + (size_t)(quarter * NCH + t) * CHUNK;
        float4 q;
        q.x = s00*og; q.y = s01*og; q.z = s02*og; q.w = s03*og; *(float4*)(base +  0) = q;
        q.x = s04*og; q.y = s05*og; q.z = s06*og; q.w = s07*og; *(float4*)(base +  4) = q;
        q.x = s08*og; q.y = s09*og; q.z = s10*og; q.w = s11*og; *(float4*)(base +  8) = q;
        q.x = s12*og; q.y = s13*og; q.z = s14*og; q.w = s15*og; *(float4*)(base + 12) = q;
    }
}

extern "C" void kernel_launch(void* const* d_in, const int* in_sizes, int n_in,
                              void* d_out, int out_size, void* d_ws, size_t ws_size,
                              hipStream_t stream)
{
    const float* audio  = (const float*)d_in[0];
    const float* params = (const float*)d_in[1];
    float* out = (float*)d_out;
    unsigned int* ws = (unsigned int*)d_ws;
    biquad_chain_kernel<<<NBLK * NBATCH, NCH, 0, stream>>>(audio, params, out, ws);
}